// Round 1
// baseline (5806.500 us; speedup 1.0000x reference)
//
#include <hip/hip_runtime.h>
#include <hip/hip_bf16.h>

#define N_NODES 40000
#define N_EDGES 640000
#define R_REL 4
#define F_IN 128
#define H_DIM 128
#define NBLK 2
#define G_GRAPHS 64
#define N_OUT 10
#define MAXDEG 10

#define BM 64
#define BK 32

__device__ __forceinline__ float relu_f(float x){ return x > 0.f ? x : 0.f; }

// ---------- degree + per-(node,rel) counts ----------
__global__ void k_deg_cnt(const int* __restrict__ src, const int* __restrict__ dst,
                          const int* __restrict__ et, int* __restrict__ deg, int* __restrict__ cnt){
  int e = blockIdx.x * blockDim.x + threadIdx.x;
  if (e >= N_EDGES) return;
  int d = dst[e];
  atomicAdd(&deg[d], 1);
  atomicAdd(&cnt[d * R_REL + et[e]], 1);
}

__global__ void k_bucket_count(const int* __restrict__ deg, int* __restrict__ bcount){
  int n = blockIdx.x * blockDim.x + threadIdx.x;
  if (n >= N_NODES) return;
  int d = deg[n]; if (d > MAXDEG) d = MAXDEG;
  atomicAdd(&bcount[d], 1);
}

__global__ void k_bucket_off(const int* __restrict__ bcount, int* __restrict__ boff, int* __restrict__ cursor){
  if (threadIdx.x == 0 && blockIdx.x == 0){
    int s = 0;
    for (int d = 0; d <= MAXDEG; ++d){ boff[d] = s; cursor[d] = s; s += bcount[d]; }
  }
}

__global__ void k_bucket_fill(const int* __restrict__ deg, int* __restrict__ cursor, int* __restrict__ perm){
  int n = blockIdx.x * blockDim.x + threadIdx.x;
  if (n >= N_NODES) return;
  int d = deg[n]; if (d > MAXDEG) d = MAXDEG;
  int pos = atomicAdd(&cursor[d], 1);
  perm[pos] = n;
}

// ---------- edge scatters (relu fused on gather) ----------
__global__ void k_rgcn_scatter(const float* __restrict__ h, const int* __restrict__ src,
                               const int* __restrict__ dst, const int* __restrict__ et,
                               float* __restrict__ sums){
  int t = blockIdx.x * blockDim.x + threadIdx.x;
  int e = t >> 5, lane = t & 31;
  if (e >= N_EDGES) return;
  int s = src[e], d = dst[e], r = et[e];
  float4 v = ((const float4*)(h + (size_t)s * H_DIM))[lane];
  float* p = sums + ((size_t)d * R_REL + r) * H_DIM + lane * 4;
  unsafeAtomicAdd(p + 0, relu_f(v.x));
  unsafeAtomicAdd(p + 1, relu_f(v.y));
  unsafeAtomicAdd(p + 2, relu_f(v.z));
  unsafeAtomicAdd(p + 3, relu_f(v.w));
}

__global__ void k_mf_scatter(const float* __restrict__ h, const int* __restrict__ src,
                             const int* __restrict__ dst, float* __restrict__ agg){
  int t = blockIdx.x * blockDim.x + threadIdx.x;
  int e = t >> 5, lane = t & 31;
  if (e >= N_EDGES) return;
  int s = src[e], d = dst[e];
  float4 v = ((const float4*)(h + (size_t)s * H_DIM))[lane];
  float* p = agg + (size_t)d * H_DIM + lane * 4;
  unsafeAtomicAdd(p + 0, relu_f(v.x));
  unsafeAtomicAdd(p + 1, relu_f(v.y));
  unsafeAtomicAdd(p + 2, relu_f(v.z));
  unsafeAtomicAdd(p + 3, relu_f(v.w));
}

// ---------- plain GEMM: C = A[M,128] @ B[128,128] + bias ----------
__global__ __launch_bounds__(256) void k_gemm0(const float* __restrict__ A, const float* __restrict__ B,
                                               const float* __restrict__ bias, float* __restrict__ C){
  __shared__ float As[BM][BK + 1];
  __shared__ float Bs[BK][H_DIM];
  int tid = threadIdx.x;
  int m0 = blockIdx.x * BM;
  int tcol = tid & 31, trow = tid >> 5;
  int arow = tid >> 2;              // row this thread loads for A
  int akb  = (tid & 3) * 8;         // first k this thread loads
  float acc[8][4];
  #pragma unroll
  for (int i = 0; i < 8; ++i)
    #pragma unroll
    for (int j = 0; j < 4; ++j) acc[i][j] = 0.f;

  for (int kc = 0; kc < F_IN; kc += BK){
    #pragma unroll
    for (int l = 0; l < 2; ++l){
      int kk4 = akb + l * 4;
      float4 v = *(const float4*)(A + (size_t)(m0 + arow) * F_IN + kc + kk4);
      As[arow][kk4 + 0] = v.x; As[arow][kk4 + 1] = v.y;
      As[arow][kk4 + 2] = v.z; As[arow][kk4 + 3] = v.w;
    }
    #pragma unroll
    for (int l = 0; l < 4; ++l){
      int f = tid + l * 256;
      int kk = f >> 5, j4 = (f & 31) * 4;
      *(float4*)&Bs[kk][j4] = *(const float4*)(B + (size_t)(kc + kk) * H_DIM + j4);
    }
    __syncthreads();
    #pragma unroll
    for (int kk = 0; kk < BK; ++kk){
      float4 bv = *(const float4*)&Bs[kk][tcol * 4];
      #pragma unroll
      for (int i = 0; i < 8; ++i){
        float a = As[trow * 8 + i][kk];
        acc[i][0] += a * bv.x; acc[i][1] += a * bv.y;
        acc[i][2] += a * bv.z; acc[i][3] += a * bv.w;
      }
    }
    __syncthreads();
  }
  float4 bb = *(const float4*)(bias + tcol * 4);
  #pragma unroll
  for (int i = 0; i < 8; ++i){
    int gr = m0 + trow * 8 + i;
    float4 o;
    o.x = acc[i][0] + bb.x; o.y = acc[i][1] + bb.y;
    o.z = acc[i][2] + bb.z; o.w = acc[i][3] + bb.w;
    *(float4*)(C + (size_t)gr * H_DIM + tcol * 4) = o;
  }
}

// ---------- RGCN: C = sum_r mean[:,r,:]@Wrel[r] + relu(h)@Wroot + b ----------
__global__ __launch_bounds__(256) void k_rgcn_gemm(const float* __restrict__ sums, const int* __restrict__ cnt,
                                                   const float* __restrict__ h, const float* __restrict__ Wrel,
                                                   const float* __restrict__ Wroot, const float* __restrict__ bias,
                                                   float* __restrict__ C){
  __shared__ float As[BM][BK + 1];
  __shared__ float Bs[BK][H_DIM];
  __shared__ float invc[BM][R_REL];
  int tid = threadIdx.x;
  int m0 = blockIdx.x * BM;
  int tcol = tid & 31, trow = tid >> 5;
  int arow = tid >> 2;
  int akb  = (tid & 3) * 8;
  { // 256 threads == 64 rows * 4 relations
    int row = tid >> 2, r = tid & 3;
    int c = cnt[(size_t)(m0 + row) * R_REL + r];
    invc[row][r] = c > 0 ? 1.f / (float)c : 0.f;
  }
  __syncthreads();
  float acc[8][4];
  #pragma unroll
  for (int i = 0; i < 8; ++i)
    #pragma unroll
    for (int j = 0; j < 4; ++j) acc[i][j] = 0.f;

  for (int srcId = 0; srcId < 5; ++srcId){
    const float* Bsrc = (srcId < 4) ? (Wrel + (size_t)srcId * H_DIM * H_DIM) : Wroot;
    float scale = (srcId < 4) ? invc[arow][srcId] : 1.f;
    for (int kc = 0; kc < H_DIM; kc += BK){
      #pragma unroll
      for (int l = 0; l < 2; ++l){
        int kk4 = akb + l * 4;
        float4 v;
        if (srcId < 4){
          v = *(const float4*)(sums + ((size_t)(m0 + arow) * R_REL + srcId) * H_DIM + kc + kk4);
          v.x *= scale; v.y *= scale; v.z *= scale; v.w *= scale;
        } else {
          v = *(const float4*)(h + (size_t)(m0 + arow) * H_DIM + kc + kk4);
          v.x = relu_f(v.x); v.y = relu_f(v.y); v.z = relu_f(v.z); v.w = relu_f(v.w);
        }
        As[arow][kk4 + 0] = v.x; As[arow][kk4 + 1] = v.y;
        As[arow][kk4 + 2] = v.z; As[arow][kk4 + 3] = v.w;
      }
      #pragma unroll
      for (int l = 0; l < 4; ++l){
        int f = tid + l * 256;
        int kk = f >> 5, j4 = (f & 31) * 4;
        *(float4*)&Bs[kk][j4] = *(const float4*)(Bsrc + (size_t)(kc + kk) * H_DIM + j4);
      }
      __syncthreads();
      #pragma unroll
      for (int kk = 0; kk < BK; ++kk){
        float4 bv = *(const float4*)&Bs[kk][tcol * 4];
        #pragma unroll
        for (int i = 0; i < 8; ++i){
          float a = As[trow * 8 + i][kk];
          acc[i][0] += a * bv.x; acc[i][1] += a * bv.y;
          acc[i][2] += a * bv.z; acc[i][3] += a * bv.w;
        }
      }
      __syncthreads();
    }
  }
  float4 bb = *(const float4*)(bias + tcol * 4);
  #pragma unroll
  for (int i = 0; i < 8; ++i){
    int gr = m0 + trow * 8 + i;
    float4 o;
    o.x = acc[i][0] + bb.x; o.y = acc[i][1] + bb.y;
    o.z = acc[i][2] + bb.z; o.w = acc[i][3] + bb.w;
    *(float4*)(C + (size_t)gr * H_DIM + tcol * 4) = o;
  }
}

// ---------- MFConv: per-degree-bucket GEMM with gathered rows ----------
__global__ __launch_bounds__(256) void k_mf_gemm(const float* __restrict__ agg, const float* __restrict__ h,
                                                 const float* __restrict__ Wl, const float* __restrict__ Wr,
                                                 const float* __restrict__ bl, const int* __restrict__ bcount,
                                                 const int* __restrict__ boff, const int* __restrict__ perm,
                                                 float* __restrict__ C){
  int t = blockIdx.x;
  int d = -1, tile = 0;
  for (int dd = 0; dd <= MAXDEG; ++dd){
    int nt = (bcount[dd] + BM - 1) >> 6;
    if (t < nt){ d = dd; tile = t; break; }
    t -= nt;
  }
  if (d < 0) return;
  int cnt_d = bcount[d];
  int start = boff[d] + tile * BM;
  int nrows = cnt_d - tile * BM; if (nrows > BM) nrows = BM;

  __shared__ int rows[BM];
  __shared__ float As[BM][BK + 1];
  __shared__ float Bs[BK][H_DIM];
  int tid = threadIdx.x;
  if (tid < BM) rows[tid] = (tid < nrows) ? perm[start + tid] : -1;
  __syncthreads();

  int tcol = tid & 31, trow = tid >> 5;
  int arow = tid >> 2;
  int akb  = (tid & 3) * 8;
  float acc[8][4];
  #pragma unroll
  for (int i = 0; i < 8; ++i)
    #pragma unroll
    for (int j = 0; j < 4; ++j) acc[i][j] = 0.f;

  int gr_load = rows[arow];
  for (int srcId = 0; srcId < 2; ++srcId){
    const float* Asrc = srcId ? h : agg;
    const float* Bsrc = (srcId ? Wr : Wl) + (size_t)d * H_DIM * H_DIM;
    for (int kc = 0; kc < H_DIM; kc += BK){
      #pragma unroll
      for (int l = 0; l < 2; ++l){
        int kk4 = akb + l * 4;
        float4 v = make_float4(0.f, 0.f, 0.f, 0.f);
        if (gr_load >= 0){
          v = *(const float4*)(Asrc + (size_t)gr_load * H_DIM + kc + kk4);
          if (srcId){ v.x = relu_f(v.x); v.y = relu_f(v.y); v.z = relu_f(v.z); v.w = relu_f(v.w); }
        }
        As[arow][kk4 + 0] = v.x; As[arow][kk4 + 1] = v.y;
        As[arow][kk4 + 2] = v.z; As[arow][kk4 + 3] = v.w;
      }
      #pragma unroll
      for (int l = 0; l < 4; ++l){
        int f = tid + l * 256;
        int kk = f >> 5, j4 = (f & 31) * 4;
        *(float4*)&Bs[kk][j4] = *(const float4*)(Bsrc + (size_t)(kc + kk) * H_DIM + j4);
      }
      __syncthreads();
      #pragma unroll
      for (int kk = 0; kk < BK; ++kk){
        float4 bv = *(const float4*)&Bs[kk][tcol * 4];
        #pragma unroll
        for (int i = 0; i < 8; ++i){
          float a = As[trow * 8 + i][kk];
          acc[i][0] += a * bv.x; acc[i][1] += a * bv.y;
          acc[i][2] += a * bv.z; acc[i][3] += a * bv.w;
        }
      }
      __syncthreads();
    }
  }
  float4 bb = *(const float4*)(bl + (size_t)d * H_DIM + tcol * 4);
  #pragma unroll
  for (int i = 0; i < 8; ++i){
    int gr = rows[trow * 8 + i];
    if (gr >= 0){
      float4 o;
      o.x = acc[i][0] + bb.x; o.y = acc[i][1] + bb.y;
      o.z = acc[i][2] + bb.z; o.w = acc[i][3] + bb.w;
      *(float4*)(C + (size_t)gr * H_DIM + tcol * 4) = o;
    }
  }
}

// ---------- pooling + MLP ----------
__global__ void k_pool(const float* __restrict__ h, const int* __restrict__ batch, float* __restrict__ pooled){
  int t = blockIdx.x * blockDim.x + threadIdx.x;
  int n = t >> 5, lane = t & 31;
  if (n >= N_NODES) return;
  int g = batch[n];
  float4 v = ((const float4*)(h + (size_t)n * H_DIM))[lane];
  float* p = pooled + (size_t)g * H_DIM + lane * 4;
  unsafeAtomicAdd(p + 0, v.x);
  unsafeAtomicAdd(p + 1, v.y);
  unsafeAtomicAdd(p + 2, v.z);
  unsafeAtomicAdd(p + 3, v.w);
}

__global__ void k_mlp1(const float* __restrict__ pooled, const float* __restrict__ W1,
                       const float* __restrict__ b1, float* __restrict__ T){
  int t = blockIdx.x * blockDim.x + threadIdx.x;
  if (t >= G_GRAPHS * H_DIM) return;
  int n = t >> 7, j = t & 127;
  float s = b1[j];
  for (int k = 0; k < H_DIM; ++k) s += pooled[n * H_DIM + k] * W1[k * H_DIM + j];
  T[t] = relu_f(s);
}

__global__ void k_mlp2(const float* __restrict__ T, const float* __restrict__ W2,
                       const float* __restrict__ b2, float* __restrict__ out){
  int t = blockIdx.x * blockDim.x + threadIdx.x;
  if (t >= G_GRAPHS * N_OUT) return;
  int n = t / N_OUT, j = t - n * N_OUT;
  float s = b2[j];
  for (int k = 0; k < H_DIM; ++k) s += T[n * H_DIM + k] * W2[k * N_OUT + j];
  out[t] = s;
}

extern "C" void kernel_launch(void* const* d_in, const int* in_sizes, int n_in,
                              void* d_out, int out_size, void* d_ws, size_t ws_size,
                              hipStream_t stream){
  const float* x      = (const float*)d_in[0];
  const int*   ei     = (const int*)d_in[1];
  const int*   ea     = (const int*)d_in[2];
  const int*   batch  = (const int*)d_in[3];
  const float* W0     = (const float*)d_in[4];
  const float* b0     = (const float*)d_in[5];
  const float* rWrel  = (const float*)d_in[6];
  const float* rWroot = (const float*)d_in[7];
  const float* rb     = (const float*)d_in[8];
  const float* mWl    = (const float*)d_in[9];
  const float* mbl    = (const float*)d_in[10];
  const float* mWr    = (const float*)d_in[11];
  const float* W1     = (const float*)d_in[12];
  const float* b1     = (const float*)d_in[13];
  const float* W2     = (const float*)d_in[14];
  const float* b2     = (const float*)d_in[15];
  float* out = (float*)d_out;

  const int* src = ei;
  const int* dst = ei + N_EDGES;

  char* ws = (char*)d_ws;
  size_t off = 0;
  auto alloc = [&](size_t bytes) -> void* {
    void* p = ws + off;
    off += (bytes + 255) & ~(size_t)255;
    return p;
  };
  float* h0     = (float*)alloc((size_t)N_NODES * H_DIM * 4);
  float* h1     = (float*)alloc((size_t)N_NODES * H_DIM * 4);
  float* sums   = (float*)alloc((size_t)N_NODES * R_REL * H_DIM * 4);
  float* agg    = sums;   // reused after k_rgcn_gemm consumes sums
  float* pooled = (float*)alloc((size_t)G_GRAPHS * H_DIM * 4);
  float* T      = (float*)alloc((size_t)G_GRAPHS * H_DIM * 4);
  int* deg      = (int*)alloc((size_t)N_NODES * 4);
  int* cnt      = (int*)alloc((size_t)N_NODES * R_REL * 4);
  int* perm     = (int*)alloc((size_t)N_NODES * 4);
  int* bcount   = (int*)alloc(16 * 4);
  int* boff     = (int*)alloc(16 * 4);
  int* cursor   = (int*)alloc(16 * 4);

  hipMemsetAsync(deg, 0, (size_t)N_NODES * 4, stream);
  hipMemsetAsync(cnt, 0, (size_t)N_NODES * R_REL * 4, stream);
  hipMemsetAsync(bcount, 0, 16 * 4, stream);
  hipMemsetAsync(pooled, 0, (size_t)G_GRAPHS * H_DIM * 4, stream);

  k_deg_cnt<<<(N_EDGES + 255) / 256, 256, 0, stream>>>(src, dst, ea, deg, cnt);
  k_bucket_count<<<(N_NODES + 255) / 256, 256, 0, stream>>>(deg, bcount);
  k_bucket_off<<<1, 1, 0, stream>>>(bcount, boff, cursor);
  k_bucket_fill<<<(N_NODES + 255) / 256, 256, 0, stream>>>(deg, cursor, perm);

  k_gemm0<<<N_NODES / BM, 256, 0, stream>>>(x, W0, b0, h0);

  float* hin = h0;
  float* hout = h1;
  for (int blk = 0; blk < NBLK; ++blk){
    hipMemsetAsync(sums, 0, (size_t)N_NODES * R_REL * H_DIM * 4, stream);
    k_rgcn_scatter<<<(N_EDGES * 32) / 256, 256, 0, stream>>>(hin, src, dst, ea, sums);
    k_rgcn_gemm<<<N_NODES / BM, 256, 0, stream>>>(sums, cnt, hin,
        rWrel + (size_t)blk * R_REL * H_DIM * H_DIM,
        rWroot + (size_t)blk * H_DIM * H_DIM,
        rb + (size_t)blk * H_DIM, hout);
    { float* tmp = hin; hin = hout; hout = tmp; }

    hipMemsetAsync(agg, 0, (size_t)N_NODES * H_DIM * 4, stream);
    k_mf_scatter<<<(N_EDGES * 32) / 256, 256, 0, stream>>>(hin, src, dst, agg);
    k_mf_gemm<<<N_NODES / BM + MAXDEG + 1, 256, 0, stream>>>(agg, hin,
        mWl + (size_t)blk * (MAXDEG + 1) * H_DIM * H_DIM,
        mWr + (size_t)blk * (MAXDEG + 1) * H_DIM * H_DIM,
        mbl + (size_t)blk * (MAXDEG + 1) * H_DIM,
        bcount, boff, perm, hout);
    { float* tmp = hin; hin = hout; hout = tmp; }
  }

  k_pool<<<(N_NODES * 32 + 255) / 256, 256, 0, stream>>>(hin, batch, pooled);
  k_mlp1<<<(G_GRAPHS * H_DIM + 255) / 256, 256, 0, stream>>>(pooled, W1, b1, T);
  k_mlp2<<<(G_GRAPHS * N_OUT + 255) / 256, 256, 0, stream>>>(T, W2, b2, out);
}

// Round 2
// 780.868 us; speedup vs baseline: 7.4360x; 7.4360x over previous
//
#include <hip/hip_runtime.h>
#include <hip/hip_bf16.h>

#define N_NODES 40000
#define N_EDGES 640000
#define R_REL 4
#define F_IN 128
#define H_DIM 128
#define NBLK 2
#define G_GRAPHS 64
#define N_OUT 10
#define MAXDEG 10

#define BM 64
#define BK 32
#define NSCAN_BLK ((N_NODES + 255) / 256)   // 157

__device__ __forceinline__ float relu_f(float x){ return x > 0.f ? x : 0.f; }

// ---------- degree ----------
__global__ void k_deg(const int* __restrict__ dst, int* __restrict__ deg){
  int e = blockIdx.x * blockDim.x + threadIdx.x;
  if (e >= N_EDGES) return;
  atomicAdd(&deg[dst[e]], 1);
}

// ---------- exclusive scan of deg -> row_ptr (3 kernels) ----------
__global__ __launch_bounds__(256) void k_scan_a(const int* __restrict__ deg,
                                                int* __restrict__ row_ptr, int* __restrict__ bsum){
  __shared__ int s[256];
  int tid = threadIdx.x;
  int i = blockIdx.x * 256 + tid;
  int v = (i < N_NODES) ? deg[i] : 0;
  s[tid] = v;
  __syncthreads();
  for (int o = 1; o < 256; o <<= 1){
    int t = (tid >= o) ? s[tid - o] : 0;
    __syncthreads();
    s[tid] += t;
    __syncthreads();
  }
  if (i < N_NODES) row_ptr[i] = s[tid] - v;        // exclusive within block
  if (tid == 255) bsum[blockIdx.x] = s[255];
}

__global__ __launch_bounds__(256) void k_scan_b(int* __restrict__ bsum, int* __restrict__ bbase){
  __shared__ int s[256];
  int tid = threadIdx.x;
  int v = (tid < NSCAN_BLK) ? bsum[tid] : 0;
  s[tid] = v;
  __syncthreads();
  for (int o = 1; o < 256; o <<= 1){
    int t = (tid >= o) ? s[tid - o] : 0;
    __syncthreads();
    s[tid] += t;
    __syncthreads();
  }
  if (tid < NSCAN_BLK) bbase[tid] = s[tid] - v;
}

__global__ __launch_bounds__(256) void k_scan_c(int* __restrict__ row_ptr, const int* __restrict__ bbase){
  int i = blockIdx.x * 256 + threadIdx.x;
  if (i < N_NODES) row_ptr[i] += bbase[blockIdx.x];
  if (i == 0) row_ptr[N_NODES] = N_EDGES;
}

// ---------- CSR fill: edges grouped by dst, payload packed (src, rel) ----------
__global__ void k_csr_fill(const int* __restrict__ src, const int* __restrict__ dst,
                           const int* __restrict__ et, const int* __restrict__ row_ptr,
                           int* __restrict__ cursor, int2* __restrict__ epk){
  int e = blockIdx.x * blockDim.x + threadIdx.x;
  if (e >= N_EDGES) return;
  int d = dst[e];
  int p = atomicAdd(&cursor[d], 1);
  epk[row_ptr[d] + p] = make_int2(src[e], et[e]);
}

// ---------- degree-bucket counting sort (hierarchical, no global hot atomics) ----------
__global__ __launch_bounds__(256) void k_bhist(const int* __restrict__ deg, int* __restrict__ bhist){
  __shared__ int lh[MAXDEG + 1];
  int tid = threadIdx.x;
  if (tid <= MAXDEG) lh[tid] = 0;
  __syncthreads();
  int i = blockIdx.x * 256 + tid;
  if (i < N_NODES){
    int d = deg[i]; if (d > MAXDEG) d = MAXDEG;
    atomicAdd(&lh[d], 1);
  }
  __syncthreads();
  if (tid <= MAXDEG) bhist[blockIdx.x * (MAXDEG + 1) + tid] = lh[tid];
}

__global__ __launch_bounds__(64) void k_bscan(const int* __restrict__ bhist, int* __restrict__ pbase,
                                              int* __restrict__ bcount, int* __restrict__ boff){
  __shared__ int cnt_s[MAXDEG + 1];
  __shared__ int off_s[MAXDEG + 1];
  int d = threadIdx.x;
  if (d <= MAXDEG){
    int run = 0;
    for (int b = 0; b < NSCAN_BLK; ++b){
      pbase[b * (MAXDEG + 1) + d] = run;
      run += bhist[b * (MAXDEG + 1) + d];
    }
    cnt_s[d] = run;
    bcount[d] = run;
  }
  __syncthreads();
  if (d == 0){
    int s = 0;
    for (int dd = 0; dd <= MAXDEG; ++dd){ off_s[dd] = s; boff[dd] = s; s += cnt_s[dd]; }
  }
  __syncthreads();
  if (d <= MAXDEG){
    int base = off_s[d];
    for (int b = 0; b < NSCAN_BLK; ++b) pbase[b * (MAXDEG + 1) + d] += base;
  }
}

__global__ __launch_bounds__(256) void k_bfill(const int* __restrict__ deg, const int* __restrict__ pbase,
                                               int* __restrict__ perm){
  __shared__ int lh[MAXDEG + 1];
  int tid = threadIdx.x;
  if (tid <= MAXDEG) lh[tid] = 0;
  __syncthreads();
  int i = blockIdx.x * 256 + tid;
  if (i < N_NODES){
    int d = deg[i]; if (d > MAXDEG) d = MAXDEG;
    int lpos = atomicAdd(&lh[d], 1);
    perm[pbase[blockIdx.x * (MAXDEG + 1) + d] + lpos] = i;
  }
}

// ---------- RGCN aggregation: one wave per node, per-relation running mean ----------
__global__ __launch_bounds__(256) void k_rgcn_agg(const float* __restrict__ h,
                                                  const int* __restrict__ row_ptr,
                                                  const int2* __restrict__ epk,
                                                  float* __restrict__ mean){
  int node = blockIdx.x * 4 + (threadIdx.x >> 6);
  int lane = threadIdx.x & 63;
  int beg = row_ptr[node], end = row_ptr[node + 1];
  float2 acc[R_REL];
  int cnt[R_REL];
  #pragma unroll
  for (int r = 0; r < R_REL; ++r){ acc[r] = make_float2(0.f, 0.f); cnt[r] = 0; }
  for (int e = beg; e < end; ++e){
    int2 pk = epk[e];
    float2 v = *(const float2*)(h + (size_t)pk.x * H_DIM + lane * 2);
    v.x = relu_f(v.x); v.y = relu_f(v.y);
    #pragma unroll
    for (int r = 0; r < R_REL; ++r){
      bool m = (pk.y == r);
      acc[r].x += m ? v.x : 0.f;
      acc[r].y += m ? v.y : 0.f;
      cnt[r]   += m ? 1 : 0;
    }
  }
  #pragma unroll
  for (int r = 0; r < R_REL; ++r){
    float inv = cnt[r] > 0 ? 1.f / (float)cnt[r] : 0.f;
    float2 o = make_float2(acc[r].x * inv, acc[r].y * inv);
    *(float2*)(mean + ((size_t)node * R_REL + r) * H_DIM + lane * 2) = o;
  }
}

// ---------- MFConv aggregation: one wave per node, plain sum ----------
__global__ __launch_bounds__(256) void k_mf_agg(const float* __restrict__ h,
                                                const int* __restrict__ row_ptr,
                                                const int2* __restrict__ epk,
                                                float* __restrict__ agg){
  int node = blockIdx.x * 4 + (threadIdx.x >> 6);
  int lane = threadIdx.x & 63;
  int beg = row_ptr[node], end = row_ptr[node + 1];
  float2 acc = make_float2(0.f, 0.f);
  for (int e = beg; e < end; ++e){
    int2 pk = epk[e];
    float2 v = *(const float2*)(h + (size_t)pk.x * H_DIM + lane * 2);
    acc.x += relu_f(v.x); acc.y += relu_f(v.y);
  }
  *(float2*)(agg + (size_t)node * H_DIM + lane * 2) = acc;
}

// ---------- plain GEMM: C = A[M,128] @ B[128,128] + bias ----------
__global__ __launch_bounds__(256) void k_gemm0(const float* __restrict__ A, const float* __restrict__ B,
                                               const float* __restrict__ bias, float* __restrict__ C){
  __shared__ float As[BM][BK + 1];
  __shared__ float Bs[BK][H_DIM];
  int tid = threadIdx.x;
  int m0 = blockIdx.x * BM;
  int tcol = tid & 31, trow = tid >> 5;
  int arow = tid >> 2;
  int akb  = (tid & 3) * 8;
  float acc[8][4];
  #pragma unroll
  for (int i = 0; i < 8; ++i)
    #pragma unroll
    for (int j = 0; j < 4; ++j) acc[i][j] = 0.f;

  for (int kc = 0; kc < F_IN; kc += BK){
    #pragma unroll
    for (int l = 0; l < 2; ++l){
      int kk4 = akb + l * 4;
      float4 v = *(const float4*)(A + (size_t)(m0 + arow) * F_IN + kc + kk4);
      As[arow][kk4 + 0] = v.x; As[arow][kk4 + 1] = v.y;
      As[arow][kk4 + 2] = v.z; As[arow][kk4 + 3] = v.w;
    }
    #pragma unroll
    for (int l = 0; l < 4; ++l){
      int f = tid + l * 256;
      int kk = f >> 5, j4 = (f & 31) * 4;
      *(float4*)&Bs[kk][j4] = *(const float4*)(B + (size_t)(kc + kk) * H_DIM + j4);
    }
    __syncthreads();
    #pragma unroll
    for (int kk = 0; kk < BK; ++kk){
      float4 bv = *(const float4*)&Bs[kk][tcol * 4];
      #pragma unroll
      for (int i = 0; i < 8; ++i){
        float a = As[trow * 8 + i][kk];
        acc[i][0] += a * bv.x; acc[i][1] += a * bv.y;
        acc[i][2] += a * bv.z; acc[i][3] += a * bv.w;
      }
    }
    __syncthreads();
  }
  float4 bb = *(const float4*)(bias + tcol * 4);
  #pragma unroll
  for (int i = 0; i < 8; ++i){
    int gr = m0 + trow * 8 + i;
    float4 o;
    o.x = acc[i][0] + bb.x; o.y = acc[i][1] + bb.y;
    o.z = acc[i][2] + bb.z; o.w = acc[i][3] + bb.w;
    *(float4*)(C + (size_t)gr * H_DIM + tcol * 4) = o;
  }
}

// ---------- RGCN GEMM: C = sum_r mean[:,r,:]@Wrel[r] + relu(h)@Wroot + b ----------
__global__ __launch_bounds__(256) void k_rgcn_gemm(const float* __restrict__ mean,
                                                   const float* __restrict__ h, const float* __restrict__ Wrel,
                                                   const float* __restrict__ Wroot, const float* __restrict__ bias,
                                                   float* __restrict__ C){
  __shared__ float As[BM][BK + 1];
  __shared__ float Bs[BK][H_DIM];
  int tid = threadIdx.x;
  int m0 = blockIdx.x * BM;
  int tcol = tid & 31, trow = tid >> 5;
  int arow = tid >> 2;
  int akb  = (tid & 3) * 8;
  float acc[8][4];
  #pragma unroll
  for (int i = 0; i < 8; ++i)
    #pragma unroll
    for (int j = 0; j < 4; ++j) acc[i][j] = 0.f;

  for (int srcId = 0; srcId < 5; ++srcId){
    const float* Bsrc = (srcId < 4) ? (Wrel + (size_t)srcId * H_DIM * H_DIM) : Wroot;
    for (int kc = 0; kc < H_DIM; kc += BK){
      #pragma unroll
      for (int l = 0; l < 2; ++l){
        int kk4 = akb + l * 4;
        float4 v;
        if (srcId < 4){
          v = *(const float4*)(mean + ((size_t)(m0 + arow) * R_REL + srcId) * H_DIM + kc + kk4);
        } else {
          v = *(const float4*)(h + (size_t)(m0 + arow) * H_DIM + kc + kk4);
          v.x = relu_f(v.x); v.y = relu_f(v.y); v.z = relu_f(v.z); v.w = relu_f(v.w);
        }
        As[arow][kk4 + 0] = v.x; As[arow][kk4 + 1] = v.y;
        As[arow][kk4 + 2] = v.z; As[arow][kk4 + 3] = v.w;
      }
      #pragma unroll
      for (int l = 0; l < 4; ++l){
        int f = tid + l * 256;
        int kk = f >> 5, j4 = (f & 31) * 4;
        *(float4*)&Bs[kk][j4] = *(const float4*)(Bsrc + (size_t)(kc + kk) * H_DIM + j4);
      }
      __syncthreads();
      #pragma unroll
      for (int kk = 0; kk < BK; ++kk){
        float4 bv = *(const float4*)&Bs[kk][tcol * 4];
        #pragma unroll
        for (int i = 0; i < 8; ++i){
          float a = As[trow * 8 + i][kk];
          acc[i][0] += a * bv.x; acc[i][1] += a * bv.y;
          acc[i][2] += a * bv.z; acc[i][3] += a * bv.w;
        }
      }
      __syncthreads();
    }
  }
  float4 bb = *(const float4*)(bias + tcol * 4);
  #pragma unroll
  for (int i = 0; i < 8; ++i){
    int gr = m0 + trow * 8 + i;
    float4 o;
    o.x = acc[i][0] + bb.x; o.y = acc[i][1] + bb.y;
    o.z = acc[i][2] + bb.z; o.w = acc[i][3] + bb.w;
    *(float4*)(C + (size_t)gr * H_DIM + tcol * 4) = o;
  }
}

// ---------- MFConv: per-degree-bucket GEMM with gathered rows ----------
__global__ __launch_bounds__(256) void k_mf_gemm(const float* __restrict__ agg, const float* __restrict__ h,
                                                 const float* __restrict__ Wl, const float* __restrict__ Wr,
                                                 const float* __restrict__ bl, const int* __restrict__ bcount,
                                                 const int* __restrict__ boff, const int* __restrict__ perm,
                                                 float* __restrict__ C){
  int t = blockIdx.x;
  int d = -1, tile = 0;
  for (int dd = 0; dd <= MAXDEG; ++dd){
    int nt = (bcount[dd] + BM - 1) >> 6;
    if (t < nt){ d = dd; tile = t; break; }
    t -= nt;
  }
  if (d < 0) return;
  int cnt_d = bcount[d];
  int start = boff[d] + tile * BM;
  int nrows = cnt_d - tile * BM; if (nrows > BM) nrows = BM;

  __shared__ int rows[BM];
  __shared__ float As[BM][BK + 1];
  __shared__ float Bs[BK][H_DIM];
  int tid = threadIdx.x;
  if (tid < BM) rows[tid] = (tid < nrows) ? perm[start + tid] : -1;
  __syncthreads();

  int tcol = tid & 31, trow = tid >> 5;
  int arow = tid >> 2;
  int akb  = (tid & 3) * 8;
  float acc[8][4];
  #pragma unroll
  for (int i = 0; i < 8; ++i)
    #pragma unroll
    for (int j = 0; j < 4; ++j) acc[i][j] = 0.f;

  int gr_load = rows[arow];
  for (int srcId = 0; srcId < 2; ++srcId){
    const float* Asrc = srcId ? h : agg;
    const float* Bsrc = (srcId ? Wr : Wl) + (size_t)d * H_DIM * H_DIM;
    for (int kc = 0; kc < H_DIM; kc += BK){
      #pragma unroll
      for (int l = 0; l < 2; ++l){
        int kk4 = akb + l * 4;
        float4 v = make_float4(0.f, 0.f, 0.f, 0.f);
        if (gr_load >= 0){
          v = *(const float4*)(Asrc + (size_t)gr_load * H_DIM + kc + kk4);
          if (srcId){ v.x = relu_f(v.x); v.y = relu_f(v.y); v.z = relu_f(v.z); v.w = relu_f(v.w); }
        }
        As[arow][kk4 + 0] = v.x; As[arow][kk4 + 1] = v.y;
        As[arow][kk4 + 2] = v.z; As[arow][kk4 + 3] = v.w;
      }
      #pragma unroll
      for (int l = 0; l < 4; ++l){
        int f = tid + l * 256;
        int kk = f >> 5, j4 = (f & 31) * 4;
        *(float4*)&Bs[kk][j4] = *(const float4*)(Bsrc + (size_t)(kc + kk) * H_DIM + j4);
      }
      __syncthreads();
      #pragma unroll
      for (int kk = 0; kk < BK; ++kk){
        float4 bv = *(const float4*)&Bs[kk][tcol * 4];
        #pragma unroll
        for (int i = 0; i < 8; ++i){
          float a = As[trow * 8 + i][kk];
          acc[i][0] += a * bv.x; acc[i][1] += a * bv.y;
          acc[i][2] += a * bv.z; acc[i][3] += a * bv.w;
        }
      }
      __syncthreads();
    }
  }
  float4 bb = *(const float4*)(bl + (size_t)d * H_DIM + tcol * 4);
  #pragma unroll
  for (int i = 0; i < 8; ++i){
    int gr = rows[trow * 8 + i];
    if (gr >= 0){
      float4 o;
      o.x = acc[i][0] + bb.x; o.y = acc[i][1] + bb.y;
      o.z = acc[i][2] + bb.z; o.w = acc[i][3] + bb.w;
      *(float4*)(C + (size_t)gr * H_DIM + tcol * 4) = o;
    }
  }
}

// ---------- graph boundaries from sorted batch_idx ----------
__global__ void k_goff(const int* __restrict__ batch, int* __restrict__ goff){
  int n = blockIdx.x * blockDim.x + threadIdx.x;
  if (n >= N_NODES) return;
  int b = batch[n];
  int bp = (n == 0) ? -1 : batch[n - 1];
  for (int g = bp + 1; g <= b; ++g) goff[g] = n;
  if (n == N_NODES - 1){
    for (int g = b + 1; g <= G_GRAPHS; ++g) goff[g] = N_NODES;
  }
}

// ---------- pooling: one block per graph, range reduction ----------
__global__ __launch_bounds__(256) void k_pool(const float* __restrict__ h, const int* __restrict__ goff,
                                              float* __restrict__ pooled){
  __shared__ float4 sred[8][32];
  int g = blockIdx.x;
  int tid = threadIdx.x;
  int rg = tid >> 5, lane = tid & 31;
  int beg = goff[g], end = goff[g + 1];
  float4 acc = make_float4(0.f, 0.f, 0.f, 0.f);
  for (int n = beg + rg; n < end; n += 8){
    float4 v = ((const float4*)(h + (size_t)n * H_DIM))[lane];
    acc.x += v.x; acc.y += v.y; acc.z += v.z; acc.w += v.w;
  }
  sred[rg][lane] = acc;
  __syncthreads();
  if (tid < 32){
    float4 s = sred[0][tid];
    #pragma unroll
    for (int r = 1; r < 8; ++r){
      float4 v = sred[r][tid];
      s.x += v.x; s.y += v.y; s.z += v.z; s.w += v.w;
    }
    *(float4*)(pooled + (size_t)g * H_DIM + tid * 4) = s;
  }
}

// ---------- MLP ----------
__global__ void k_mlp1(const float* __restrict__ pooled, const float* __restrict__ W1,
                       const float* __restrict__ b1, float* __restrict__ T){
  int t = blockIdx.x * blockDim.x + threadIdx.x;
  if (t >= G_GRAPHS * H_DIM) return;
  int n = t >> 7, j = t & 127;
  float s = b1[j];
  for (int k = 0; k < H_DIM; ++k) s += pooled[n * H_DIM + k] * W1[k * H_DIM + j];
  T[t] = relu_f(s);
}

__global__ void k_mlp2(const float* __restrict__ T, const float* __restrict__ W2,
                       const float* __restrict__ b2, float* __restrict__ out){
  int t = blockIdx.x * blockDim.x + threadIdx.x;
  if (t >= G_GRAPHS * N_OUT) return;
  int n = t / N_OUT, j = t - n * N_OUT;
  float s = b2[j];
  for (int k = 0; k < H_DIM; ++k) s += T[n * H_DIM + k] * W2[k * N_OUT + j];
  out[t] = s;
}

extern "C" void kernel_launch(void* const* d_in, const int* in_sizes, int n_in,
                              void* d_out, int out_size, void* d_ws, size_t ws_size,
                              hipStream_t stream){
  const float* x      = (const float*)d_in[0];
  const int*   ei     = (const int*)d_in[1];
  const int*   ea     = (const int*)d_in[2];
  const int*   batch  = (const int*)d_in[3];
  const float* W0     = (const float*)d_in[4];
  const float* b0     = (const float*)d_in[5];
  const float* rWrel  = (const float*)d_in[6];
  const float* rWroot = (const float*)d_in[7];
  const float* rb     = (const float*)d_in[8];
  const float* mWl    = (const float*)d_in[9];
  const float* mbl    = (const float*)d_in[10];
  const float* mWr    = (const float*)d_in[11];
  const float* W1     = (const float*)d_in[12];
  const float* b1     = (const float*)d_in[13];
  const float* W2     = (const float*)d_in[14];
  const float* b2     = (const float*)d_in[15];
  float* out = (float*)d_out;

  const int* src = ei;
  const int* dst = ei + N_EDGES;

  char* ws = (char*)d_ws;
  size_t off = 0;
  auto alloc = [&](size_t bytes) -> void* {
    void* p = ws + off;
    off += (bytes + 255) & ~(size_t)255;
    return p;
  };
  float* h0     = (float*)alloc((size_t)N_NODES * H_DIM * 4);
  float* h1     = (float*)alloc((size_t)N_NODES * H_DIM * 4);
  float* mean   = (float*)alloc((size_t)N_NODES * R_REL * H_DIM * 4);
  float* agg    = mean;                       // MFConv agg reuses first 20MB of mean
  float* pooled = (float*)alloc((size_t)G_GRAPHS * H_DIM * 4);
  float* T      = (float*)alloc((size_t)G_GRAPHS * H_DIM * 4);
  int* deg      = (int*)alloc((size_t)N_NODES * 4);
  int* row_ptr  = (int*)alloc((size_t)(N_NODES + 1) * 4);
  int* cursor   = (int*)alloc((size_t)N_NODES * 4);
  int2* epk     = (int2*)alloc((size_t)N_EDGES * 8);
  int* bsum     = (int*)alloc((size_t)NSCAN_BLK * 4);
  int* bbase    = (int*)alloc((size_t)NSCAN_BLK * 4);
  int* bhist    = (int*)alloc((size_t)NSCAN_BLK * (MAXDEG + 1) * 4);
  int* pbase    = (int*)alloc((size_t)NSCAN_BLK * (MAXDEG + 1) * 4);
  int* perm     = (int*)alloc((size_t)N_NODES * 4);
  int* bcount   = (int*)alloc(16 * 4);
  int* boff     = (int*)alloc(16 * 4);
  int* goff     = (int*)alloc((size_t)(G_GRAPHS + 1) * 4);

  hipMemsetAsync(deg, 0, (size_t)N_NODES * 4, stream);
  hipMemsetAsync(cursor, 0, (size_t)N_NODES * 4, stream);

  // graph structure (once per call)
  k_deg<<<(N_EDGES + 255) / 256, 256, 0, stream>>>(dst, deg);
  k_scan_a<<<NSCAN_BLK, 256, 0, stream>>>(deg, row_ptr, bsum);
  k_scan_b<<<1, 256, 0, stream>>>(bsum, bbase);
  k_scan_c<<<NSCAN_BLK, 256, 0, stream>>>(row_ptr, bbase);
  k_csr_fill<<<(N_EDGES + 255) / 256, 256, 0, stream>>>(src, dst, ea, row_ptr, cursor, epk);
  k_bhist<<<NSCAN_BLK, 256, 0, stream>>>(deg, bhist);
  k_bscan<<<1, 64, 0, stream>>>(bhist, pbase, bcount, boff);
  k_bfill<<<NSCAN_BLK, 256, 0, stream>>>(deg, pbase, perm);
  k_goff<<<(N_NODES + 255) / 256, 256, 0, stream>>>(batch, goff);

  k_gemm0<<<N_NODES / BM, 256, 0, stream>>>(x, W0, b0, h0);

  float* hin = h0;
  float* hout = h1;
  for (int blk = 0; blk < NBLK; ++blk){
    k_rgcn_agg<<<N_NODES / 4, 256, 0, stream>>>(hin, row_ptr, epk, mean);
    k_rgcn_gemm<<<N_NODES / BM, 256, 0, stream>>>(mean, hin,
        rWrel + (size_t)blk * R_REL * H_DIM * H_DIM,
        rWroot + (size_t)blk * H_DIM * H_DIM,
        rb + (size_t)blk * H_DIM, hout);
    { float* tmp = hin; hin = hout; hout = tmp; }

    k_mf_agg<<<N_NODES / 4, 256, 0, stream>>>(hin, row_ptr, epk, agg);
    k_mf_gemm<<<N_NODES / BM + MAXDEG + 1, 256, 0, stream>>>(agg, hin,
        mWl + (size_t)blk * (MAXDEG + 1) * H_DIM * H_DIM,
        mWr + (size_t)blk * (MAXDEG + 1) * H_DIM * H_DIM,
        mbl + (size_t)blk * (MAXDEG + 1) * H_DIM,
        bcount, boff, perm, hout);
    { float* tmp = hin; hin = hout; hout = tmp; }
  }

  k_pool<<<G_GRAPHS, 256, 0, stream>>>(hin, goff, pooled);
  k_mlp1<<<(G_GRAPHS * H_DIM + 255) / 256, 256, 0, stream>>>(pooled, W1, b1, T);
  k_mlp2<<<(G_GRAPHS * N_OUT + 255) / 256, 256, 0, stream>>>(T, W2, b2, out);
}

// Round 3
// 641.751 us; speedup vs baseline: 9.0479x; 1.2168x over previous
//
#include <hip/hip_runtime.h>
#include <hip/hip_bf16.h>

#define N_NODES 40000
#define N_EDGES 640000
#define R_REL 4
#define F_IN 128
#define H_DIM 128
#define NBLK 2
#define G_GRAPHS 64
#define N_OUT 10
#define MAXDEG 10
#define NSCAN_BLK ((N_NODES + 255) / 256)   // 157

typedef unsigned short u16;
typedef float f32x4 __attribute__((ext_vector_type(4)));
typedef short bf16x8 __attribute__((ext_vector_type(8)));

__device__ __forceinline__ float relu_f(float x){ return x > 0.f ? x : 0.f; }

// fp32 -> bf16 round-to-nearest-even
__device__ __forceinline__ u16 f2bf(float f){
  union { float f; unsigned int u; } v; v.f = f;
  unsigned int r = v.u + 0x7fffu + ((v.u >> 16) & 1u);
  return (u16)(r >> 16);
}
__device__ __forceinline__ float b2f(u16 u){
  union { unsigned int u; float f; } v; v.u = ((unsigned int)u) << 16; return v.f;
}

// ---------- degree ----------
__global__ void k_deg(const int* __restrict__ dst, int* __restrict__ deg){
  int e = blockIdx.x * blockDim.x + threadIdx.x;
  if (e >= N_EDGES) return;
  atomicAdd(&deg[dst[e]], 1);
}

// ---------- exclusive scan of deg -> row_ptr ----------
__global__ __launch_bounds__(256) void k_scan_a(const int* __restrict__ deg,
                                                int* __restrict__ row_ptr, int* __restrict__ bsum){
  __shared__ int s[256];
  int tid = threadIdx.x;
  int i = blockIdx.x * 256 + tid;
  int v = (i < N_NODES) ? deg[i] : 0;
  s[tid] = v;
  __syncthreads();
  for (int o = 1; o < 256; o <<= 1){
    int t = (tid >= o) ? s[tid - o] : 0;
    __syncthreads();
    s[tid] += t;
    __syncthreads();
  }
  if (i < N_NODES) row_ptr[i] = s[tid] - v;
  if (tid == 255) bsum[blockIdx.x] = s[255];
}

__global__ __launch_bounds__(256) void k_scan_b(int* __restrict__ bsum, int* __restrict__ bbase){
  __shared__ int s[256];
  int tid = threadIdx.x;
  int v = (tid < NSCAN_BLK) ? bsum[tid] : 0;
  s[tid] = v;
  __syncthreads();
  for (int o = 1; o < 256; o <<= 1){
    int t = (tid >= o) ? s[tid - o] : 0;
    __syncthreads();
    s[tid] += t;
    __syncthreads();
  }
  if (tid < NSCAN_BLK) bbase[tid] = s[tid] - v;
}

__global__ __launch_bounds__(256) void k_scan_c(int* __restrict__ row_ptr, const int* __restrict__ bbase){
  int i = blockIdx.x * 256 + threadIdx.x;
  if (i < N_NODES) row_ptr[i] += bbase[blockIdx.x];
  if (i == 0) row_ptr[N_NODES] = N_EDGES;
}

// ---------- CSR fill ----------
__global__ void k_csr_fill(const int* __restrict__ src, const int* __restrict__ dst,
                           const int* __restrict__ et, const int* __restrict__ row_ptr,
                           int* __restrict__ cursor, int2* __restrict__ epk){
  int e = blockIdx.x * blockDim.x + threadIdx.x;
  if (e >= N_EDGES) return;
  int d = dst[e];
  int p = atomicAdd(&cursor[d], 1);
  epk[row_ptr[d] + p] = make_int2(src[e], et[e]);
}

// ---------- degree-bucket counting sort ----------
__global__ __launch_bounds__(256) void k_bhist(const int* __restrict__ deg, int* __restrict__ bhist){
  __shared__ int lh[MAXDEG + 1];
  int tid = threadIdx.x;
  if (tid <= MAXDEG) lh[tid] = 0;
  __syncthreads();
  int i = blockIdx.x * 256 + tid;
  if (i < N_NODES){
    int d = deg[i]; if (d > MAXDEG) d = MAXDEG;
    atomicAdd(&lh[d], 1);
  }
  __syncthreads();
  if (tid <= MAXDEG) bhist[blockIdx.x * (MAXDEG + 1) + tid] = lh[tid];
}

__global__ __launch_bounds__(64) void k_bscan(const int* __restrict__ bhist, int* __restrict__ pbase,
                                              int* __restrict__ bcount, int* __restrict__ boff){
  __shared__ int cnt_s[MAXDEG + 1];
  __shared__ int off_s[MAXDEG + 1];
  int d = threadIdx.x;
  if (d <= MAXDEG){
    int run = 0;
    for (int b = 0; b < NSCAN_BLK; ++b){
      pbase[b * (MAXDEG + 1) + d] = run;
      run += bhist[b * (MAXDEG + 1) + d];
    }
    cnt_s[d] = run;
    bcount[d] = run;
  }
  __syncthreads();
  if (d == 0){
    int s = 0;
    for (int dd = 0; dd <= MAXDEG; ++dd){ off_s[dd] = s; boff[dd] = s; s += cnt_s[dd]; }
  }
  __syncthreads();
  if (d <= MAXDEG){
    int base = off_s[d];
    for (int b = 0; b < NSCAN_BLK; ++b) pbase[b * (MAXDEG + 1) + d] += base;
  }
}

__global__ __launch_bounds__(256) void k_bfill(const int* __restrict__ deg, const int* __restrict__ pbase,
                                               int* __restrict__ perm){
  __shared__ int lh[MAXDEG + 1];
  int tid = threadIdx.x;
  if (tid <= MAXDEG) lh[tid] = 0;
  __syncthreads();
  int i = blockIdx.x * 256 + tid;
  if (i < N_NODES){
    int d = deg[i]; if (d > MAXDEG) d = MAXDEG;
    int lpos = atomicAdd(&lh[d], 1);
    perm[pbase[blockIdx.x * (MAXDEG + 1) + d] + lpos] = i;
  }
}

// ---------- weight convert: [nmat][128][128] fp32 -> transposed [nmat][n][k] bf16 ----------
__global__ __launch_bounds__(256) void k_cvtW(const float* __restrict__ src, u16* __restrict__ dst){
  __shared__ float s[32][33];
  int mat = blockIdx.x >> 4;
  int tile = blockIdx.x & 15;
  int tr = (tile >> 2) * 32, tc = (tile & 3) * 32;
  const float* S = src + (size_t)mat * 16384;
  u16* D = dst + (size_t)mat * 16384;
  int c = threadIdx.x & 31, r0 = threadIdx.x >> 5;
  #pragma unroll
  for (int i = 0; i < 4; ++i){
    int r = r0 + i * 8;
    s[r][c] = S[(size_t)(tr + r) * 128 + tc + c];
  }
  __syncthreads();
  #pragma unroll
  for (int i = 0; i < 4; ++i){
    int r = r0 + i * 8;
    D[(size_t)(tc + r) * 128 + tr + c] = f2bf(s[c][r]);
  }
}

// ---------- x fp32 -> bf16 ----------
__global__ void k_cvtx(const float* __restrict__ x, u16* __restrict__ xb){
  int t = blockIdx.x * 256 + threadIdx.x;
  if (t >= (N_NODES * H_DIM) / 4) return;
  float4 v = ((const float4*)x)[t];
  uint2 o = make_uint2((unsigned)f2bf(v.x) | ((unsigned)f2bf(v.y) << 16),
                       (unsigned)f2bf(v.z) | ((unsigned)f2bf(v.w) << 16));
  ((uint2*)xb)[t] = o;
}

// ---------- RGCN aggregation (bf16 in/out, fp32 accum) ----------
__global__ __launch_bounds__(256) void k_rgcn_agg(const u16* __restrict__ hb,
                                                  const int* __restrict__ row_ptr,
                                                  const int2* __restrict__ epk,
                                                  u16* __restrict__ meanb){
  int node = blockIdx.x * 4 + (threadIdx.x >> 6);
  int lane = threadIdx.x & 63;
  int beg = row_ptr[node], end = row_ptr[node + 1];
  float a0[R_REL], a1[R_REL]; int cnt[R_REL];
  #pragma unroll
  for (int r = 0; r < R_REL; ++r){ a0[r] = 0.f; a1[r] = 0.f; cnt[r] = 0; }
  for (int e = beg; e < end; ++e){
    int2 pk = epk[e];
    unsigned v = *(const unsigned*)(hb + (size_t)pk.x * H_DIM + lane * 2);
    float f0 = b2f((u16)v), f1 = b2f((u16)(v >> 16));   // hb is already relu'd
    #pragma unroll
    for (int r = 0; r < R_REL; ++r){
      bool m = (pk.y == r);
      a0[r] += m ? f0 : 0.f;
      a1[r] += m ? f1 : 0.f;
      cnt[r] += m ? 1 : 0;
    }
  }
  #pragma unroll
  for (int r = 0; r < R_REL; ++r){
    float inv = cnt[r] > 0 ? 1.f / (float)cnt[r] : 0.f;
    unsigned o = (unsigned)f2bf(a0[r] * inv) | ((unsigned)f2bf(a1[r] * inv) << 16);
    *(unsigned*)(meanb + ((size_t)node * R_REL + r) * H_DIM + lane * 2) = o;
  }
}

// ---------- MFConv aggregation (sum) ----------
__global__ __launch_bounds__(256) void k_mf_agg(const u16* __restrict__ hb,
                                                const int* __restrict__ row_ptr,
                                                const int2* __restrict__ epk,
                                                u16* __restrict__ aggb){
  int node = blockIdx.x * 4 + (threadIdx.x >> 6);
  int lane = threadIdx.x & 63;
  int beg = row_ptr[node], end = row_ptr[node + 1];
  float a0 = 0.f, a1 = 0.f;
  for (int e = beg; e < end; ++e){
    int2 pk = epk[e];
    unsigned v = *(const unsigned*)(hb + (size_t)pk.x * H_DIM + lane * 2);
    a0 += b2f((u16)v); a1 += b2f((u16)(v >> 16));
  }
  unsigned o = (unsigned)f2bf(a0) | ((unsigned)f2bf(a1) << 16);
  *(unsigned*)(aggb + (size_t)node * H_DIM + lane * 2) = o;
}

// ---------- MFMA GEMM: hb_out = bf16(relu(xb @ W0^T(T) + b0)) ----------
__global__ __launch_bounds__(256) void k_gemm0(const u16* __restrict__ xb, const u16* __restrict__ wt,
                                               const float* __restrict__ bias, u16* __restrict__ hbo){
  int w = threadIdx.x >> 6, lane = threadIdx.x & 63;
  int m0 = blockIdx.x * 64 + w * 16;
  int arow = lane & 15, kg = lane >> 4;
  f32x4 acc[8];
  #pragma unroll
  for (int ct = 0; ct < 8; ++ct) acc[ct] = (f32x4){0.f, 0.f, 0.f, 0.f};
  const u16* Arow = xb + (size_t)(m0 + arow) * F_IN;
  #pragma unroll
  for (int kk = 0; kk < 4; ++kk){
    int k0 = kk * 32 + kg * 8;
    bf16x8 a = *(const bf16x8*)(Arow + k0);
    #pragma unroll
    for (int ct = 0; ct < 8; ++ct){
      bf16x8 b = *(const bf16x8*)(wt + (size_t)(ct * 16 + arow) * F_IN + k0);
      acc[ct] = __builtin_amdgcn_mfma_f32_16x16x32_bf16(a, b, acc[ct], 0, 0, 0);
    }
  }
  #pragma unroll
  for (int ct = 0; ct < 8; ++ct){
    int col = ct * 16 + arow;
    float bb = bias[col];
    #pragma unroll
    for (int j = 0; j < 4; ++j){
      int gr = m0 + kg * 4 + j;
      hbo[(size_t)gr * H_DIM + col] = f2bf(relu_f(acc[ct][j] + bb));
    }
  }
}

// ---------- RGCN MFMA GEMM: K = 5*128 (4 relation means + root) ----------
__global__ __launch_bounds__(256) void k_rgcn_gemm(const u16* __restrict__ meanb, const u16* __restrict__ hb,
                                                   const u16* __restrict__ wrel, const u16* __restrict__ wroot,
                                                   const float* __restrict__ bias, u16* __restrict__ hbo){
  int w = threadIdx.x >> 6, lane = threadIdx.x & 63;
  int m0 = blockIdx.x * 64 + w * 16;
  int arow = lane & 15, kg = lane >> 4;
  f32x4 acc[8];
  #pragma unroll
  for (int ct = 0; ct < 8; ++ct) acc[ct] = (f32x4){0.f, 0.f, 0.f, 0.f};
  #pragma unroll
  for (int seg = 0; seg < 5; ++seg){
    const u16* Arow = (seg < 4) ? meanb + ((size_t)(m0 + arow) * R_REL + seg) * H_DIM
                                : hb + (size_t)(m0 + arow) * H_DIM;
    const u16* WT = (seg < 4) ? wrel + (size_t)seg * 16384 : wroot;
    #pragma unroll
    for (int kk = 0; kk < 4; ++kk){
      int k0 = kk * 32 + kg * 8;
      bf16x8 a = *(const bf16x8*)(Arow + k0);
      #pragma unroll
      for (int ct = 0; ct < 8; ++ct){
        bf16x8 b = *(const bf16x8*)(WT + (size_t)(ct * 16 + arow) * H_DIM + k0);
        acc[ct] = __builtin_amdgcn_mfma_f32_16x16x32_bf16(a, b, acc[ct], 0, 0, 0);
      }
    }
  }
  #pragma unroll
  for (int ct = 0; ct < 8; ++ct){
    int col = ct * 16 + arow;
    float bb = bias[col];
    #pragma unroll
    for (int j = 0; j < 4; ++j){
      int gr = m0 + kg * 4 + j;
      hbo[(size_t)gr * H_DIM + col] = f2bf(relu_f(acc[ct][j] + bb));
    }
  }
}

// ---------- MFConv MFMA GEMM: per-degree buckets, gathered rows ----------
template<int FINAL>
__global__ __launch_bounds__(256) void k_mf_gemm(const u16* __restrict__ aggb, const u16* __restrict__ hb,
                                                 const u16* __restrict__ wl, const u16* __restrict__ wr,
                                                 const float* __restrict__ bl,
                                                 const int* __restrict__ bcount, const int* __restrict__ boff,
                                                 const int* __restrict__ perm,
                                                 u16* __restrict__ hbo, float* __restrict__ hf){
  int t = blockIdx.x;
  int d = -1, tile = 0;
  for (int dd = 0; dd <= MAXDEG; ++dd){
    int nt = (bcount[dd] + 63) >> 6;
    if (t < nt){ d = dd; tile = t; break; }
    t -= nt;
  }
  if (d < 0) return;
  int cnt_d = bcount[d];
  int start = boff[d] + tile * 64;
  int nrows = cnt_d - tile * 64; if (nrows > 64) nrows = 64;

  __shared__ int rows[64];
  int tid = threadIdx.x;
  if (tid < 64) rows[tid] = (tid < nrows) ? perm[start + tid] : -1;
  __syncthreads();

  int w = tid >> 6, lane = tid & 63;
  int arow = lane & 15, kg = lane >> 4;
  int myrow = rows[w * 16 + arow];
  f32x4 acc[8];
  #pragma unroll
  for (int ct = 0; ct < 8; ++ct) acc[ct] = (f32x4){0.f, 0.f, 0.f, 0.f};
  bf16x8 zf = {0, 0, 0, 0, 0, 0, 0, 0};

  #pragma unroll
  for (int seg = 0; seg < 2; ++seg){
    const u16* Abase = seg ? hb : aggb;
    const u16* WT = (seg ? wr : wl) + (size_t)d * 16384;
    #pragma unroll
    for (int kk = 0; kk < 4; ++kk){
      int k0 = kk * 32 + kg * 8;
      bf16x8 a = (myrow >= 0) ? *(const bf16x8*)(Abase + (size_t)myrow * H_DIM + k0) : zf;
      #pragma unroll
      for (int ct = 0; ct < 8; ++ct){
        bf16x8 b = *(const bf16x8*)(WT + (size_t)(ct * 16 + arow) * H_DIM + k0);
        acc[ct] = __builtin_amdgcn_mfma_f32_16x16x32_bf16(a, b, acc[ct], 0, 0, 0);
      }
    }
  }
  #pragma unroll
  for (int ct = 0; ct < 8; ++ct){
    int col = ct * 16 + arow;
    float bb = bl[(size_t)d * H_DIM + col];
    #pragma unroll
    for (int j = 0; j < 4; ++j){
      int gr = rows[w * 16 + kg * 4 + j];
      if (gr >= 0){
        float v = acc[ct][j] + bb;
        if (FINAL) hf[(size_t)gr * H_DIM + col] = v;
        else       hbo[(size_t)gr * H_DIM + col] = f2bf(relu_f(v));
      }
    }
  }
}

// ---------- graph boundaries ----------
__global__ void k_goff(const int* __restrict__ batch, int* __restrict__ goff){
  int n = blockIdx.x * blockDim.x + threadIdx.x;
  if (n >= N_NODES) return;
  int b = batch[n];
  int bp = (n == 0) ? -1 : batch[n - 1];
  for (int g = bp + 1; g <= b; ++g) goff[g] = n;
  if (n == N_NODES - 1){
    for (int g = b + 1; g <= G_GRAPHS; ++g) goff[g] = N_NODES;
  }
}

// ---------- pooling ----------
__global__ __launch_bounds__(256) void k_pool(const float* __restrict__ h, const int* __restrict__ goff,
                                              float* __restrict__ pooled){
  __shared__ float4 sred[8][32];
  int g = blockIdx.x;
  int tid = threadIdx.x;
  int rg = tid >> 5, lane = tid & 31;
  int beg = goff[g], end = goff[g + 1];
  float4 acc = make_float4(0.f, 0.f, 0.f, 0.f);
  for (int n = beg + rg; n < end; n += 8){
    float4 v = ((const float4*)(h + (size_t)n * H_DIM))[lane];
    acc.x += v.x; acc.y += v.y; acc.z += v.z; acc.w += v.w;
  }
  sred[rg][lane] = acc;
  __syncthreads();
  if (tid < 32){
    float4 s = sred[0][tid];
    #pragma unroll
    for (int r = 1; r < 8; ++r){
      float4 v = sred[r][tid];
      s.x += v.x; s.y += v.y; s.z += v.z; s.w += v.w;
    }
    *(float4*)(pooled + (size_t)g * H_DIM + tid * 4) = s;
  }
}

// ---------- MLP ----------
__global__ void k_mlp1(const float* __restrict__ pooled, const float* __restrict__ W1,
                       const float* __restrict__ b1, float* __restrict__ T){
  int t = blockIdx.x * blockDim.x + threadIdx.x;
  if (t >= G_GRAPHS * H_DIM) return;
  int n = t >> 7, j = t & 127;
  float s = b1[j];
  for (int k = 0; k < H_DIM; ++k) s += pooled[n * H_DIM + k] * W1[k * H_DIM + j];
  T[t] = relu_f(s);
}

__global__ void k_mlp2(const float* __restrict__ T, const float* __restrict__ W2,
                       const float* __restrict__ b2, float* __restrict__ out){
  int t = blockIdx.x * blockDim.x + threadIdx.x;
  if (t >= G_GRAPHS * N_OUT) return;
  int n = t / N_OUT, j = t - n * N_OUT;
  float s = b2[j];
  for (int k = 0; k < H_DIM; ++k) s += T[n * H_DIM + k] * W2[k * N_OUT + j];
  out[t] = s;
}

extern "C" void kernel_launch(void* const* d_in, const int* in_sizes, int n_in,
                              void* d_out, int out_size, void* d_ws, size_t ws_size,
                              hipStream_t stream){
  const float* x      = (const float*)d_in[0];
  const int*   ei     = (const int*)d_in[1];
  const int*   ea     = (const int*)d_in[2];
  const int*   batch  = (const int*)d_in[3];
  const float* W0     = (const float*)d_in[4];
  const float* b0     = (const float*)d_in[5];
  const float* rWrel  = (const float*)d_in[6];
  const float* rWroot = (const float*)d_in[7];
  const float* rb     = (const float*)d_in[8];
  const float* mWl    = (const float*)d_in[9];
  const float* mbl    = (const float*)d_in[10];
  const float* mWr    = (const float*)d_in[11];
  const float* W1     = (const float*)d_in[12];
  const float* b1     = (const float*)d_in[13];
  const float* W2     = (const float*)d_in[14];
  const float* b2     = (const float*)d_in[15];
  float* out = (float*)d_out;

  const int* src = ei;
  const int* dst = ei + N_EDGES;

  char* ws = (char*)d_ws;
  size_t off = 0;
  auto alloc = [&](size_t bytes) -> void* {
    void* p = ws + off;
    off += (bytes + 255) & ~(size_t)255;
    return p;
  };
  u16* xb      = (u16*)alloc((size_t)N_NODES * H_DIM * 2);
  u16* hbA     = (u16*)alloc((size_t)N_NODES * H_DIM * 2);
  u16* hbB     = (u16*)alloc((size_t)N_NODES * H_DIM * 2);
  u16* meanb   = (u16*)alloc((size_t)N_NODES * R_REL * H_DIM * 2);
  u16* aggb    = meanb;  // reuse
  float* hf    = (float*)alloc((size_t)N_NODES * H_DIM * 4);
  u16* wt0     = (u16*)alloc((size_t)1 * 16384 * 2);
  u16* wtRel   = (u16*)alloc((size_t)NBLK * R_REL * 16384 * 2);
  u16* wtRoot  = (u16*)alloc((size_t)NBLK * 16384 * 2);
  u16* wtWl    = (u16*)alloc((size_t)NBLK * (MAXDEG + 1) * 16384 * 2);
  u16* wtWr    = (u16*)alloc((size_t)NBLK * (MAXDEG + 1) * 16384 * 2);
  float* pooled = (float*)alloc((size_t)G_GRAPHS * H_DIM * 4);
  float* T      = (float*)alloc((size_t)G_GRAPHS * H_DIM * 4);
  int* deg      = (int*)alloc((size_t)N_NODES * 4);
  int* row_ptr  = (int*)alloc((size_t)(N_NODES + 1) * 4);
  int* cursor   = (int*)alloc((size_t)N_NODES * 4);
  int2* epk     = (int2*)alloc((size_t)N_EDGES * 8);
  int* bsum     = (int*)alloc((size_t)NSCAN_BLK * 4);
  int* bbase    = (int*)alloc((size_t)NSCAN_BLK * 4);
  int* bhist    = (int*)alloc((size_t)NSCAN_BLK * (MAXDEG + 1) * 4);
  int* pbase    = (int*)alloc((size_t)NSCAN_BLK * (MAXDEG + 1) * 4);
  int* perm     = (int*)alloc((size_t)N_NODES * 4);
  int* bcount   = (int*)alloc(16 * 4);
  int* boff     = (int*)alloc(16 * 4);
  int* goff     = (int*)alloc((size_t)(G_GRAPHS + 1) * 4);

  hipMemsetAsync(deg, 0, (size_t)N_NODES * 4, stream);
  hipMemsetAsync(cursor, 0, (size_t)N_NODES * 4, stream);

  // graph structure
  k_deg<<<(N_EDGES + 255) / 256, 256, 0, stream>>>(dst, deg);
  k_scan_a<<<NSCAN_BLK, 256, 0, stream>>>(deg, row_ptr, bsum);
  k_scan_b<<<1, 256, 0, stream>>>(bsum, bbase);
  k_scan_c<<<NSCAN_BLK, 256, 0, stream>>>(row_ptr, bbase);
  k_csr_fill<<<(N_EDGES + 255) / 256, 256, 0, stream>>>(src, dst, ea, row_ptr, cursor, epk);
  k_bhist<<<NSCAN_BLK, 256, 0, stream>>>(deg, bhist);
  k_bscan<<<1, 64, 0, stream>>>(bhist, pbase, bcount, boff);
  k_bfill<<<NSCAN_BLK, 256, 0, stream>>>(deg, pbase, perm);
  k_goff<<<(N_NODES + 255) / 256, 256, 0, stream>>>(batch, goff);

  // weight + input conversion (bf16, weights transposed)
  k_cvtW<<<1 * 16, 256, 0, stream>>>(W0, wt0);
  k_cvtW<<<NBLK * R_REL * 16, 256, 0, stream>>>(rWrel, wtRel);
  k_cvtW<<<NBLK * 16, 256, 0, stream>>>(rWroot, wtRoot);
  k_cvtW<<<NBLK * (MAXDEG + 1) * 16, 256, 0, stream>>>(mWl, wtWl);
  k_cvtW<<<NBLK * (MAXDEG + 1) * 16, 256, 0, stream>>>(mWr, wtWr);
  k_cvtx<<<(N_NODES * H_DIM / 4 + 255) / 256, 256, 0, stream>>>(x, xb);

  k_gemm0<<<N_NODES / 64, 256, 0, stream>>>(xb, wt0, b0, hbA);

  u16* hin = hbA;
  u16* hout = hbB;
  for (int blk = 0; blk < NBLK; ++blk){
    k_rgcn_agg<<<N_NODES / 4, 256, 0, stream>>>(hin, row_ptr, epk, meanb);
    k_rgcn_gemm<<<N_NODES / 64, 256, 0, stream>>>(meanb, hin,
        wtRel + (size_t)blk * R_REL * 16384,
        wtRoot + (size_t)blk * 16384,
        rb + (size_t)blk * H_DIM, hout);
    { u16* tmp = hin; hin = hout; hout = tmp; }

    k_mf_agg<<<N_NODES / 4, 256, 0, stream>>>(hin, row_ptr, epk, aggb);
    const u16* wl_b = wtWl + (size_t)blk * (MAXDEG + 1) * 16384;
    const u16* wr_b = wtWr + (size_t)blk * (MAXDEG + 1) * 16384;
    const float* bl_b = mbl + (size_t)blk * (MAXDEG + 1) * H_DIM;
    int grid_mf = N_NODES / 64 + MAXDEG + 1;
    if (blk == NBLK - 1)
      k_mf_gemm<1><<<grid_mf, 256, 0, stream>>>(aggb, hin, wl_b, wr_b, bl_b,
                                                bcount, boff, perm, hout, hf);
    else
      k_mf_gemm<0><<<grid_mf, 256, 0, stream>>>(aggb, hin, wl_b, wr_b, bl_b,
                                                bcount, boff, perm, hout, hf);
    { u16* tmp = hin; hin = hout; hout = tmp; }
  }

  k_pool<<<G_GRAPHS, 256, 0, stream>>>(hf, goff, pooled);
  k_mlp1<<<(G_GRAPHS * H_DIM + 255) / 256, 256, 0, stream>>>(pooled, W1, b1, T);
  k_mlp2<<<(G_GRAPHS * N_OUT + 255) / 256, 256, 0, stream>>>(T, W2, b2, out);
}

// Round 4
// 497.232 us; speedup vs baseline: 11.6776x; 1.2906x over previous
//
#include <hip/hip_runtime.h>
#include <hip/hip_bf16.h>

#define N_NODES 40000
#define N_EDGES 640000
#define R_REL 4
#define F_IN 128
#define H_DIM 128
#define NBLK 2
#define G_GRAPHS 64
#define N_OUT 10
#define MAXDEG 10
#define NSCAN_BLK ((N_NODES + 255) / 256)   // 157

typedef unsigned short u16;
typedef float f32x4 __attribute__((ext_vector_type(4)));
typedef short bf16x8 __attribute__((ext_vector_type(8)));

__device__ __forceinline__ float relu_f(float x){ return x > 0.f ? x : 0.f; }

// fp32 -> bf16 round-to-nearest-even
__device__ __forceinline__ u16 f2bf(float f){
  union { float f; unsigned int u; } v; v.f = f;
  unsigned int r = v.u + 0x7fffu + ((v.u >> 16) & 1u);
  return (u16)(r >> 16);
}
__device__ __forceinline__ float b2f(u16 u){
  union { unsigned int u; float f; } v; v.u = ((unsigned int)u) << 16; return v.f;
}
__device__ __forceinline__ float blo(unsigned v){ return b2f((u16)v); }
__device__ __forceinline__ float bhi(unsigned v){ return b2f((u16)(v >> 16)); }

// ---------- per-(node,rel) counts ----------
__global__ void k_cnt(const int* __restrict__ dst, const int* __restrict__ et, int* __restrict__ cnt4){
  int e = blockIdx.x * blockDim.x + threadIdx.x;
  if (e >= N_EDGES) return;
  atomicAdd(&cnt4[dst[e] * R_REL + et[e]], 1);
}

// ---------- scan A: deg = rowsum(cnt4), block scan, per-block degree histogram ----------
__global__ __launch_bounds__(256) void k_scan_a(const int* __restrict__ cnt4, int* __restrict__ deg,
                                                int* __restrict__ row_ptr, int* __restrict__ bsum,
                                                int* __restrict__ bhist){
  __shared__ int s[256];
  __shared__ int lh[16];
  int tid = threadIdx.x;
  int i = blockIdx.x * 256 + tid;
  if (tid < 16) lh[tid] = 0;
  int d = 0;
  if (i < N_NODES){
    int4 c = *(const int4*)(cnt4 + (size_t)i * 4);
    d = c.x + c.y + c.z + c.w;
    deg[i] = d;
  }
  s[tid] = d;
  __syncthreads();
  if (i < N_NODES){
    int dc = d > MAXDEG ? MAXDEG : d;
    atomicAdd(&lh[dc], 1);
  }
  for (int o = 1; o < 256; o <<= 1){
    int t = (tid >= o) ? s[tid - o] : 0;
    __syncthreads();
    s[tid] += t;
    __syncthreads();
  }
  if (i < N_NODES) row_ptr[i] = s[tid] - d;
  if (tid == 255) bsum[blockIdx.x] = s[255];
  if (tid <= MAXDEG) bhist[blockIdx.x * (MAXDEG + 1) + tid] = lh[tid];
}

__global__ __launch_bounds__(256) void k_scan_b(int* __restrict__ bsum, int* __restrict__ bbase){
  __shared__ int s[256];
  int tid = threadIdx.x;
  int v = (tid < NSCAN_BLK) ? bsum[tid] : 0;
  s[tid] = v;
  __syncthreads();
  for (int o = 1; o < 256; o <<= 1){
    int t = (tid >= o) ? s[tid - o] : 0;
    __syncthreads();
    s[tid] += t;
    __syncthreads();
  }
  if (tid < NSCAN_BLK) bbase[tid] = s[tid] - v;
}

// ---------- scan C: finalize row_ptr, emit absolute per-(node,rel) offsets ----------
__global__ __launch_bounds__(256) void k_scan_c(int* __restrict__ row_ptr, const int* __restrict__ bbase,
                                                const int* __restrict__ cnt4, int* __restrict__ rel_off){
  int i = blockIdx.x * 256 + threadIdx.x;
  if (i < N_NODES){
    int base = row_ptr[i] + bbase[blockIdx.x];
    row_ptr[i] = base;
    int4 c = *(const int4*)(cnt4 + (size_t)i * 4);
    int4 o;
    o.x = base;
    o.y = base + c.x;
    o.z = o.y + c.y;
    o.w = o.z + c.z;
    *(int4*)(rel_off + (size_t)i * 4) = o;
  }
  if (i == 0) row_ptr[N_NODES] = N_EDGES;
}

// ---------- CSR fill: edges grouped by (dst, rel), payload = src only ----------
__global__ void k_csr_fill(const int* __restrict__ src, const int* __restrict__ dst,
                           const int* __restrict__ et, const int* __restrict__ rel_off,
                           int* __restrict__ cursor, int* __restrict__ esrc){
  int e = blockIdx.x * blockDim.x + threadIdx.x;
  if (e >= N_EDGES) return;
  int cell = dst[e] * R_REL + et[e];
  int p = atomicAdd(&cursor[cell], 1);
  esrc[rel_off[cell] + p] = src[e];
}

// ---------- degree-bucket counting sort (bhist produced by k_scan_a) ----------
__global__ __launch_bounds__(64) void k_bscan(const int* __restrict__ bhist, int* __restrict__ pbase,
                                              int* __restrict__ bcount, int* __restrict__ boff){
  __shared__ int cnt_s[MAXDEG + 1];
  __shared__ int off_s[MAXDEG + 1];
  int d = threadIdx.x;
  if (d <= MAXDEG){
    int run = 0;
    for (int b = 0; b < NSCAN_BLK; ++b){
      pbase[b * (MAXDEG + 1) + d] = run;
      run += bhist[b * (MAXDEG + 1) + d];
    }
    cnt_s[d] = run;
    bcount[d] = run;
  }
  __syncthreads();
  if (d == 0){
    int s = 0;
    for (int dd = 0; dd <= MAXDEG; ++dd){ off_s[dd] = s; boff[dd] = s; s += cnt_s[dd]; }
  }
  __syncthreads();
  if (d <= MAXDEG){
    int base = off_s[d];
    for (int b = 0; b < NSCAN_BLK; ++b) pbase[b * (MAXDEG + 1) + d] += base;
  }
}

__global__ __launch_bounds__(256) void k_bfill(const int* __restrict__ deg, const int* __restrict__ pbase,
                                               int* __restrict__ perm){
  __shared__ int lh[MAXDEG + 1];
  int tid = threadIdx.x;
  if (tid <= MAXDEG) lh[tid] = 0;
  __syncthreads();
  int i = blockIdx.x * 256 + tid;
  if (i < N_NODES){
    int d = deg[i]; if (d > MAXDEG) d = MAXDEG;
    int lpos = atomicAdd(&lh[d], 1);
    perm[pbase[blockIdx.x * (MAXDEG + 1) + d] + lpos] = i;
  }
}

// ---------- all weight tensors: fp32 [mats][128][128] -> bf16 transposed [mats][n][k] ----------
__global__ __launch_bounds__(256) void k_cvtW_all(const float* __restrict__ s0, const float* __restrict__ s1,
                                                  const float* __restrict__ s2, const float* __restrict__ s3,
                                                  const float* __restrict__ s4,
                                                  u16* __restrict__ d0, u16* __restrict__ d1,
                                                  u16* __restrict__ d2, u16* __restrict__ d3,
                                                  u16* __restrict__ d4){
  __shared__ float s[32][33];
  int b = blockIdx.x;
  int m = b >> 4, tile = b & 15;
  const float* S; u16* D; int base;
  if (m < 1){ S = s0; D = d0; base = m; }
  else if (m < 9){ S = s1; D = d1; base = m - 1; }
  else if (m < 11){ S = s2; D = d2; base = m - 9; }
  else if (m < 33){ S = s3; D = d3; base = m - 11; }
  else { S = s4; D = d4; base = m - 33; }
  S += (size_t)base * 16384;
  D += (size_t)base * 16384;
  int tr = (tile >> 2) * 32, tc = (tile & 3) * 32;
  int c = threadIdx.x & 31, r0 = threadIdx.x >> 5;
  #pragma unroll
  for (int i = 0; i < 4; ++i){
    int r = r0 + i * 8;
    s[r][c] = S[(size_t)(tr + r) * 128 + tc + c];
  }
  __syncthreads();
  #pragma unroll
  for (int i = 0; i < 4; ++i){
    int r = r0 + i * 8;
    D[(size_t)(tc + r) * 128 + tr + c] = f2bf(s[c][r]);
  }
}

// ---------- x fp32 -> bf16 ----------
__global__ void k_cvtx(const float* __restrict__ x, u16* __restrict__ xb){
  int t = blockIdx.x * 256 + threadIdx.x;
  if (t >= (N_NODES * H_DIM) / 4) return;
  float4 v = ((const float4*)x)[t];
  uint2 o = make_uint2((unsigned)f2bf(v.x) | ((unsigned)f2bf(v.y) << 16),
                       (unsigned)f2bf(v.z) | ((unsigned)f2bf(v.w) << 16));
  ((uint2*)xb)[t] = o;
}

// ---------- RGCN aggregation: relation-sorted segments, plain sums, unrolled ----------
__global__ __launch_bounds__(256) void k_rgcn_agg(const u16* __restrict__ hb,
                                                  const int* __restrict__ rel_off,
                                                  const int* __restrict__ row_ptr,
                                                  const int* __restrict__ esrc,
                                                  u16* __restrict__ meanb){
  int node = blockIdx.x * 4 + (threadIdx.x >> 6);
  int lane = threadIdx.x & 63;
  int4 ro = *(const int4*)(rel_off + (size_t)node * 4);
  int nend = row_ptr[node + 1];
  int begs[5] = {ro.x, ro.y, ro.z, ro.w, nend};
  #pragma unroll
  for (int r = 0; r < R_REL; ++r){
    int beg = begs[r], end = begs[r + 1];
    float a0 = 0.f, a1 = 0.f;
    int e = beg;
    for (; e + 4 <= end; e += 4){
      int s0 = esrc[e], s1 = esrc[e + 1], s2 = esrc[e + 2], s3 = esrc[e + 3];
      unsigned v0 = *(const unsigned*)(hb + (size_t)s0 * H_DIM + lane * 2);
      unsigned v1 = *(const unsigned*)(hb + (size_t)s1 * H_DIM + lane * 2);
      unsigned v2 = *(const unsigned*)(hb + (size_t)s2 * H_DIM + lane * 2);
      unsigned v3 = *(const unsigned*)(hb + (size_t)s3 * H_DIM + lane * 2);
      a0 += blo(v0) + blo(v1) + blo(v2) + blo(v3);
      a1 += bhi(v0) + bhi(v1) + bhi(v2) + bhi(v3);
    }
    for (; e < end; ++e){
      unsigned v = *(const unsigned*)(hb + (size_t)esrc[e] * H_DIM + lane * 2);
      a0 += blo(v); a1 += bhi(v);
    }
    int c = end - beg;
    float inv = c > 0 ? 1.f / (float)c : 0.f;
    unsigned o = (unsigned)f2bf(a0 * inv) | ((unsigned)f2bf(a1 * inv) << 16);
    *(unsigned*)(meanb + ((size_t)node * R_REL + r) * H_DIM + lane * 2) = o;
  }
}

// ---------- MFConv aggregation: whole-row sum, unrolled ----------
__global__ __launch_bounds__(256) void k_mf_agg(const u16* __restrict__ hb,
                                                const int* __restrict__ row_ptr,
                                                const int* __restrict__ esrc,
                                                u16* __restrict__ aggb){
  int node = blockIdx.x * 4 + (threadIdx.x >> 6);
  int lane = threadIdx.x & 63;
  int beg = row_ptr[node], end = row_ptr[node + 1];
  float a0 = 0.f, a1 = 0.f;
  int e = beg;
  for (; e + 4 <= end; e += 4){
    int s0 = esrc[e], s1 = esrc[e + 1], s2 = esrc[e + 2], s3 = esrc[e + 3];
    unsigned v0 = *(const unsigned*)(hb + (size_t)s0 * H_DIM + lane * 2);
    unsigned v1 = *(const unsigned*)(hb + (size_t)s1 * H_DIM + lane * 2);
    unsigned v2 = *(const unsigned*)(hb + (size_t)s2 * H_DIM + lane * 2);
    unsigned v3 = *(const unsigned*)(hb + (size_t)s3 * H_DIM + lane * 2);
    a0 += blo(v0) + blo(v1) + blo(v2) + blo(v3);
    a1 += bhi(v0) + bhi(v1) + bhi(v2) + bhi(v3);
  }
  for (; e < end; ++e){
    unsigned v = *(const unsigned*)(hb + (size_t)esrc[e] * H_DIM + lane * 2);
    a0 += blo(v); a1 += bhi(v);
  }
  unsigned o = (unsigned)f2bf(a0) | ((unsigned)f2bf(a1) << 16);
  *(unsigned*)(aggb + (size_t)node * H_DIM + lane * 2) = o;
}

// ---------- MFMA GEMM: hb_out = bf16(relu(xb @ W0T + b0)) ----------
__global__ __launch_bounds__(256) void k_gemm0(const u16* __restrict__ xb, const u16* __restrict__ wt,
                                               const float* __restrict__ bias, u16* __restrict__ hbo){
  int w = threadIdx.x >> 6, lane = threadIdx.x & 63;
  int m0 = blockIdx.x * 64 + w * 16;
  int arow = lane & 15, kg = lane >> 4;
  f32x4 acc[8];
  #pragma unroll
  for (int ct = 0; ct < 8; ++ct) acc[ct] = (f32x4){0.f, 0.f, 0.f, 0.f};
  const u16* Arow = xb + (size_t)(m0 + arow) * F_IN;
  #pragma unroll
  for (int kk = 0; kk < 4; ++kk){
    int k0 = kk * 32 + kg * 8;
    bf16x8 a = *(const bf16x8*)(Arow + k0);
    #pragma unroll
    for (int ct = 0; ct < 8; ++ct){
      bf16x8 b = *(const bf16x8*)(wt + (size_t)(ct * 16 + arow) * F_IN + k0);
      acc[ct] = __builtin_amdgcn_mfma_f32_16x16x32_bf16(a, b, acc[ct], 0, 0, 0);
    }
  }
  #pragma unroll
  for (int ct = 0; ct < 8; ++ct){
    int col = ct * 16 + arow;
    float bb = bias[col];
    #pragma unroll
    for (int j = 0; j < 4; ++j){
      int gr = m0 + kg * 4 + j;
      hbo[(size_t)gr * H_DIM + col] = f2bf(relu_f(acc[ct][j] + bb));
    }
  }
}

// ---------- RGCN MFMA GEMM: K = 5*128 ----------
__global__ __launch_bounds__(256) void k_rgcn_gemm(const u16* __restrict__ meanb, const u16* __restrict__ hb,
                                                   const u16* __restrict__ wrel, const u16* __restrict__ wroot,
                                                   const float* __restrict__ bias, u16* __restrict__ hbo){
  int w = threadIdx.x >> 6, lane = threadIdx.x & 63;
  int m0 = blockIdx.x * 64 + w * 16;
  int arow = lane & 15, kg = lane >> 4;
  f32x4 acc[8];
  #pragma unroll
  for (int ct = 0; ct < 8; ++ct) acc[ct] = (f32x4){0.f, 0.f, 0.f, 0.f};
  #pragma unroll
  for (int seg = 0; seg < 5; ++seg){
    const u16* Arow = (seg < 4) ? meanb + ((size_t)(m0 + arow) * R_REL + seg) * H_DIM
                                : hb + (size_t)(m0 + arow) * H_DIM;
    const u16* WT = (seg < 4) ? wrel + (size_t)seg * 16384 : wroot;
    #pragma unroll
    for (int kk = 0; kk < 4; ++kk){
      int k0 = kk * 32 + kg * 8;
      bf16x8 a = *(const bf16x8*)(Arow + k0);
      #pragma unroll
      for (int ct = 0; ct < 8; ++ct){
        bf16x8 b = *(const bf16x8*)(WT + (size_t)(ct * 16 + arow) * H_DIM + k0);
        acc[ct] = __builtin_amdgcn_mfma_f32_16x16x32_bf16(a, b, acc[ct], 0, 0, 0);
      }
    }
  }
  #pragma unroll
  for (int ct = 0; ct < 8; ++ct){
    int col = ct * 16 + arow;
    float bb = bias[col];
    #pragma unroll
    for (int j = 0; j < 4; ++j){
      int gr = m0 + kg * 4 + j;
      hbo[(size_t)gr * H_DIM + col] = f2bf(relu_f(acc[ct][j] + bb));
    }
  }
}

// ---------- MFConv MFMA GEMM: per-degree buckets ----------
template<int FINAL>
__global__ __launch_bounds__(256) void k_mf_gemm(const u16* __restrict__ aggb, const u16* __restrict__ hb,
                                                 const u16* __restrict__ wl, const u16* __restrict__ wr,
                                                 const float* __restrict__ bl,
                                                 const int* __restrict__ bcount, const int* __restrict__ boff,
                                                 const int* __restrict__ perm,
                                                 u16* __restrict__ hbo, float* __restrict__ hf){
  int t = blockIdx.x;
  int d = -1, tile = 0;
  for (int dd = 0; dd <= MAXDEG; ++dd){
    int nt = (bcount[dd] + 63) >> 6;
    if (t < nt){ d = dd; tile = t; break; }
    t -= nt;
  }
  if (d < 0) return;
  int cnt_d = bcount[d];
  int start = boff[d] + tile * 64;
  int nrows = cnt_d - tile * 64; if (nrows > 64) nrows = 64;

  __shared__ int rows[64];
  int tid = threadIdx.x;
  if (tid < 64) rows[tid] = (tid < nrows) ? perm[start + tid] : -1;
  __syncthreads();

  int w = tid >> 6, lane = tid & 63;
  int arow = lane & 15, kg = lane >> 4;
  int myrow = rows[w * 16 + arow];
  f32x4 acc[8];
  #pragma unroll
  for (int ct = 0; ct < 8; ++ct) acc[ct] = (f32x4){0.f, 0.f, 0.f, 0.f};
  bf16x8 zf = {0, 0, 0, 0, 0, 0, 0, 0};

  #pragma unroll
  for (int seg = 0; seg < 2; ++seg){
    const u16* Abase = seg ? hb : aggb;
    const u16* WT = (seg ? wr : wl) + (size_t)d * 16384;
    #pragma unroll
    for (int kk = 0; kk < 4; ++kk){
      int k0 = kk * 32 + kg * 8;
      bf16x8 a = (myrow >= 0) ? *(const bf16x8*)(Abase + (size_t)myrow * H_DIM + k0) : zf;
      #pragma unroll
      for (int ct = 0; ct < 8; ++ct){
        bf16x8 b = *(const bf16x8*)(WT + (size_t)(ct * 16 + arow) * H_DIM + k0);
        acc[ct] = __builtin_amdgcn_mfma_f32_16x16x32_bf16(a, b, acc[ct], 0, 0, 0);
      }
    }
  }
  #pragma unroll
  for (int ct = 0; ct < 8; ++ct){
    int col = ct * 16 + arow;
    float bb = bl[(size_t)d * H_DIM + col];
    #pragma unroll
    for (int j = 0; j < 4; ++j){
      int gr = rows[w * 16 + kg * 4 + j];
      if (gr >= 0){
        float v = acc[ct][j] + bb;
        if (FINAL) hf[(size_t)gr * H_DIM + col] = v;
        else       hbo[(size_t)gr * H_DIM + col] = f2bf(relu_f(v));
      }
    }
  }
}

// ---------- graph boundaries ----------
__global__ void k_goff(const int* __restrict__ batch, int* __restrict__ goff){
  int n = blockIdx.x * blockDim.x + threadIdx.x;
  if (n >= N_NODES) return;
  int b = batch[n];
  int bp = (n == 0) ? -1 : batch[n - 1];
  for (int g = bp + 1; g <= b; ++g) goff[g] = n;
  if (n == N_NODES - 1){
    for (int g = b + 1; g <= G_GRAPHS; ++g) goff[g] = N_NODES;
  }
}

// ---------- pooling ----------
__global__ __launch_bounds__(256) void k_pool(const float* __restrict__ h, const int* __restrict__ goff,
                                              float* __restrict__ pooled){
  __shared__ float4 sred[8][32];
  int g = blockIdx.x;
  int tid = threadIdx.x;
  int rg = tid >> 5, lane = tid & 31;
  int beg = goff[g], end = goff[g + 1];
  float4 acc = make_float4(0.f, 0.f, 0.f, 0.f);
  for (int n = beg + rg; n < end; n += 8){
    float4 v = ((const float4*)(h + (size_t)n * H_DIM))[lane];
    acc.x += v.x; acc.y += v.y; acc.z += v.z; acc.w += v.w;
  }
  sred[rg][lane] = acc;
  __syncthreads();
  if (tid < 32){
    float4 s = sred[0][tid];
    #pragma unroll
    for (int r = 1; r < 8; ++r){
      float4 v = sred[r][tid];
      s.x += v.x; s.y += v.y; s.z += v.z; s.w += v.w;
    }
    *(float4*)(pooled + (size_t)g * H_DIM + tid * 4) = s;
  }
}

// ---------- MLP ----------
__global__ void k_mlp1(const float* __restrict__ pooled, const float* __restrict__ W1,
                       const float* __restrict__ b1, float* __restrict__ T){
  int t = blockIdx.x * blockDim.x + threadIdx.x;
  if (t >= G_GRAPHS * H_DIM) return;
  int n = t >> 7, j = t & 127;
  float s = b1[j];
  for (int k = 0; k < H_DIM; ++k) s += pooled[n * H_DIM + k] * W1[k * H_DIM + j];
  T[t] = relu_f(s);
}

__global__ void k_mlp2(const float* __restrict__ T, const float* __restrict__ W2,
                       const float* __restrict__ b2, float* __restrict__ out){
  int t = blockIdx.x * blockDim.x + threadIdx.x;
  if (t >= G_GRAPHS * N_OUT) return;
  int n = t / N_OUT, j = t - n * N_OUT;
  float s = b2[j];
  for (int k = 0; k < H_DIM; ++k) s += T[n * H_DIM + k] * W2[k * N_OUT + j];
  out[t] = s;
}

extern "C" void kernel_launch(void* const* d_in, const int* in_sizes, int n_in,
                              void* d_out, int out_size, void* d_ws, size_t ws_size,
                              hipStream_t stream){
  const float* x      = (const float*)d_in[0];
  const int*   ei     = (const int*)d_in[1];
  const int*   ea     = (const int*)d_in[2];
  const int*   batch  = (const int*)d_in[3];
  const float* W0     = (const float*)d_in[4];
  const float* b0     = (const float*)d_in[5];
  const float* rWrel  = (const float*)d_in[6];
  const float* rWroot = (const float*)d_in[7];
  const float* rb     = (const float*)d_in[8];
  const float* mWl    = (const float*)d_in[9];
  const float* mbl    = (const float*)d_in[10];
  const float* mWr    = (const float*)d_in[11];
  const float* W1     = (const float*)d_in[12];
  const float* b1     = (const float*)d_in[13];
  const float* W2     = (const float*)d_in[14];
  const float* b2     = (const float*)d_in[15];
  float* out = (float*)d_out;

  const int* src = ei;
  const int* dst = ei + N_EDGES;

  char* ws = (char*)d_ws;
  size_t off = 0;
  auto alloc = [&](size_t bytes) -> void* {
    void* p = ws + off;
    off += (bytes + 255) & ~(size_t)255;
    return p;
  };
  u16* xb      = (u16*)alloc((size_t)N_NODES * H_DIM * 2);
  u16* hbA     = (u16*)alloc((size_t)N_NODES * H_DIM * 2);
  u16* hbB     = (u16*)alloc((size_t)N_NODES * H_DIM * 2);
  u16* meanb   = (u16*)alloc((size_t)N_NODES * R_REL * H_DIM * 2);
  u16* aggb    = meanb;  // reuse
  float* hf    = (float*)alloc((size_t)N_NODES * H_DIM * 4);
  u16* wt0     = (u16*)alloc((size_t)1 * 16384 * 2);
  u16* wtRel   = (u16*)alloc((size_t)NBLK * R_REL * 16384 * 2);
  u16* wtRoot  = (u16*)alloc((size_t)NBLK * 16384 * 2);
  u16* wtWl    = (u16*)alloc((size_t)NBLK * (MAXDEG + 1) * 16384 * 2);
  u16* wtWr    = (u16*)alloc((size_t)NBLK * (MAXDEG + 1) * 16384 * 2);
  float* pooled = (float*)alloc((size_t)G_GRAPHS * H_DIM * 4);
  float* T      = (float*)alloc((size_t)G_GRAPHS * H_DIM * 4);
  int* cnt4     = (int*)alloc((size_t)N_NODES * R_REL * 4);
  int* deg      = (int*)alloc((size_t)N_NODES * 4);
  int* row_ptr  = (int*)alloc((size_t)(N_NODES + 1) * 4);
  int* rel_off  = (int*)alloc((size_t)N_NODES * R_REL * 4);
  int* cursor   = (int*)alloc((size_t)N_NODES * R_REL * 4);
  int* esrc     = (int*)alloc((size_t)N_EDGES * 4);
  int* bsum     = (int*)alloc((size_t)NSCAN_BLK * 4);
  int* bbase    = (int*)alloc((size_t)NSCAN_BLK * 4);
  int* bhist    = (int*)alloc((size_t)NSCAN_BLK * (MAXDEG + 1) * 4);
  int* pbase    = (int*)alloc((size_t)NSCAN_BLK * (MAXDEG + 1) * 4);
  int* perm     = (int*)alloc((size_t)N_NODES * 4);
  int* bcount   = (int*)alloc(16 * 4);
  int* boff     = (int*)alloc(16 * 4);
  int* goff     = (int*)alloc((size_t)(G_GRAPHS + 1) * 4);

  hipMemsetAsync(cnt4, 0, (size_t)N_NODES * R_REL * 4, stream);
  hipMemsetAsync(cursor, 0, (size_t)N_NODES * R_REL * 4, stream);

  // graph structure
  k_cnt<<<(N_EDGES + 255) / 256, 256, 0, stream>>>(dst, ea, cnt4);
  k_scan_a<<<NSCAN_BLK, 256, 0, stream>>>(cnt4, deg, row_ptr, bsum, bhist);
  k_scan_b<<<1, 256, 0, stream>>>(bsum, bbase);
  k_scan_c<<<NSCAN_BLK, 256, 0, stream>>>(row_ptr, bbase, cnt4, rel_off);
  k_csr_fill<<<(N_EDGES + 255) / 256, 256, 0, stream>>>(src, dst, ea, rel_off, cursor, esrc);
  k_bscan<<<1, 64, 0, stream>>>(bhist, pbase, bcount, boff);
  k_bfill<<<NSCAN_BLK, 256, 0, stream>>>(deg, pbase, perm);
  k_goff<<<(N_NODES + 255) / 256, 256, 0, stream>>>(batch, goff);

  // weight + input conversion
  k_cvtW_all<<<55 * 16, 256, 0, stream>>>(W0, rWrel, rWroot, mWl, mWr,
                                          wt0, wtRel, wtRoot, wtWl, wtWr);
  k_cvtx<<<(N_NODES * H_DIM / 4 + 255) / 256, 256, 0, stream>>>(x, xb);

  k_gemm0<<<N_NODES / 64, 256, 0, stream>>>(xb, wt0, b0, hbA);

  u16* hin = hbA;
  u16* hout = hbB;
  for (int blk = 0; blk < NBLK; ++blk){
    k_rgcn_agg<<<N_NODES / 4, 256, 0, stream>>>(hin, rel_off, row_ptr, esrc, meanb);
    k_rgcn_gemm<<<N_NODES / 64, 256, 0, stream>>>(meanb, hin,
        wtRel + (size_t)blk * R_REL * 16384,
        wtRoot + (size_t)blk * 16384,
        rb + (size_t)blk * H_DIM, hout);
    { u16* tmp = hin; hin = hout; hout = tmp; }

    k_mf_agg<<<N_NODES / 4, 256, 0, stream>>>(hin, row_ptr, esrc, aggb);
    const u16* wl_b = wtWl + (size_t)blk * (MAXDEG + 1) * 16384;
    const u16* wr_b = wtWr + (size_t)blk * (MAXDEG + 1) * 16384;
    const float* bl_b = mbl + (size_t)blk * (MAXDEG + 1) * H_DIM;
    int grid_mf = N_NODES / 64 + MAXDEG + 1;
    if (blk == NBLK - 1)
      k_mf_gemm<1><<<grid_mf, 256, 0, stream>>>(aggb, hin, wl_b, wr_b, bl_b,
                                                bcount, boff, perm, hout, hf);
    else
      k_mf_gemm<0><<<grid_mf, 256, 0, stream>>>(aggb, hin, wl_b, wr_b, bl_b,
                                                bcount, boff, perm, hout, hf);
    { u16* tmp = hin; hin = hout; hout = tmp; }
  }

  k_pool<<<G_GRAPHS, 256, 0, stream>>>(hf, goff, pooled);
  k_mlp1<<<(G_GRAPHS * H_DIM + 255) / 256, 256, 0, stream>>>(pooled, W1, b1, T);
  k_mlp2<<<(G_GRAPHS * N_OUT + 255) / 256, 256, 0, stream>>>(T, W2, b2, out);
}

// Round 5
// 485.164 us; speedup vs baseline: 11.9681x; 1.0249x over previous
//
#include <hip/hip_runtime.h>
#include <hip/hip_bf16.h>

#define N_NODES 40000
#define N_EDGES 640000
#define R_REL 4
#define F_IN 128
#define H_DIM 128
#define NBLK 2
#define G_GRAPHS 64
#define N_OUT 10
#define MAXDEG 10
#define NSCAN_BLK ((N_NODES + 255) / 256)   // 157

typedef unsigned short u16;
typedef float f32x4 __attribute__((ext_vector_type(4)));
typedef short bf16x8 __attribute__((ext_vector_type(8)));

__device__ __forceinline__ float relu_f(float x){ return x > 0.f ? x : 0.f; }

// fp32 -> bf16 round-to-nearest-even
__device__ __forceinline__ u16 f2bf(float f){
  union { float f; unsigned int u; } v; v.f = f;
  unsigned int r = v.u + 0x7fffu + ((v.u >> 16) & 1u);
  return (u16)(r >> 16);
}
__device__ __forceinline__ float b2f(u16 u){
  union { unsigned int u; float f; } v; v.u = ((unsigned int)u) << 16; return v.f;
}
__device__ __forceinline__ float blo(unsigned v){ return b2f((u16)v); }
__device__ __forceinline__ float bhi(unsigned v){ return b2f((u16)(v >> 16)); }

// ---------- per-(node,rel) counts ----------
__global__ void k_cnt(const int* __restrict__ dst, const int* __restrict__ et, int* __restrict__ cnt4){
  int e = blockIdx.x * blockDim.x + threadIdx.x;
  if (e >= N_EDGES) return;
  atomicAdd(&cnt4[dst[e] * R_REL + et[e]], 1);
}

// ---------- scan A ----------
__global__ __launch_bounds__(256) void k_scan_a(const int* __restrict__ cnt4, int* __restrict__ deg,
                                                int* __restrict__ row_ptr, int* __restrict__ bsum,
                                                int* __restrict__ bhist){
  __shared__ int s[256];
  __shared__ int lh[16];
  int tid = threadIdx.x;
  int i = blockIdx.x * 256 + tid;
  if (tid < 16) lh[tid] = 0;
  int d = 0;
  if (i < N_NODES){
    int4 c = *(const int4*)(cnt4 + (size_t)i * 4);
    d = c.x + c.y + c.z + c.w;
    deg[i] = d;
  }
  s[tid] = d;
  __syncthreads();
  if (i < N_NODES){
    int dc = d > MAXDEG ? MAXDEG : d;
    atomicAdd(&lh[dc], 1);
  }
  for (int o = 1; o < 256; o <<= 1){
    int t = (tid >= o) ? s[tid - o] : 0;
    __syncthreads();
    s[tid] += t;
    __syncthreads();
  }
  if (i < N_NODES) row_ptr[i] = s[tid] - d;
  if (tid == 255) bsum[blockIdx.x] = s[255];
  if (tid <= MAXDEG) bhist[blockIdx.x * (MAXDEG + 1) + tid] = lh[tid];
}

__global__ __launch_bounds__(256) void k_scan_b(int* __restrict__ bsum, int* __restrict__ bbase){
  __shared__ int s[256];
  int tid = threadIdx.x;
  int v = (tid < NSCAN_BLK) ? bsum[tid] : 0;
  s[tid] = v;
  __syncthreads();
  for (int o = 1; o < 256; o <<= 1){
    int t = (tid >= o) ? s[tid - o] : 0;
    __syncthreads();
    s[tid] += t;
    __syncthreads();
  }
  if (tid < NSCAN_BLK) bbase[tid] = s[tid] - v;
}

__global__ __launch_bounds__(256) void k_scan_c(int* __restrict__ row_ptr, const int* __restrict__ bbase,
                                                const int* __restrict__ cnt4, int* __restrict__ rel_off){
  int i = blockIdx.x * 256 + threadIdx.x;
  if (i < N_NODES){
    int base = row_ptr[i] + bbase[blockIdx.x];
    row_ptr[i] = base;
    int4 c = *(const int4*)(cnt4 + (size_t)i * 4);
    int4 o;
    o.x = base;
    o.y = base + c.x;
    o.z = o.y + c.y;
    o.w = o.z + c.z;
    *(int4*)(rel_off + (size_t)i * 4) = o;
  }
  if (i == 0) row_ptr[N_NODES] = N_EDGES;
}

// ---------- CSR fill ----------
__global__ void k_csr_fill(const int* __restrict__ src, const int* __restrict__ dst,
                           const int* __restrict__ et, const int* __restrict__ rel_off,
                           int* __restrict__ cursor, int* __restrict__ esrc){
  int e = blockIdx.x * blockDim.x + threadIdx.x;
  if (e >= N_EDGES) return;
  int cell = dst[e] * R_REL + et[e];
  int p = atomicAdd(&cursor[cell], 1);
  esrc[rel_off[cell] + p] = src[e];
}

// ---------- degree-bucket counting sort ----------
__global__ __launch_bounds__(64) void k_bscan(const int* __restrict__ bhist, int* __restrict__ pbase,
                                              int* __restrict__ bcount, int* __restrict__ boff){
  __shared__ int cnt_s[MAXDEG + 1];
  __shared__ int off_s[MAXDEG + 1];
  int d = threadIdx.x;
  if (d <= MAXDEG){
    int run = 0;
    for (int b = 0; b < NSCAN_BLK; ++b){
      pbase[b * (MAXDEG + 1) + d] = run;
      run += bhist[b * (MAXDEG + 1) + d];
    }
    cnt_s[d] = run;
    bcount[d] = run;
  }
  __syncthreads();
  if (d == 0){
    int s = 0;
    for (int dd = 0; dd <= MAXDEG; ++dd){ off_s[dd] = s; boff[dd] = s; s += cnt_s[dd]; }
  }
  __syncthreads();
  if (d <= MAXDEG){
    int base = off_s[d];
    for (int b = 0; b < NSCAN_BLK; ++b) pbase[b * (MAXDEG + 1) + d] += base;
  }
}

__global__ __launch_bounds__(256) void k_bfill(const int* __restrict__ deg, const int* __restrict__ pbase,
                                               int* __restrict__ perm){
  __shared__ int lh[MAXDEG + 1];
  int tid = threadIdx.x;
  if (tid <= MAXDEG) lh[tid] = 0;
  __syncthreads();
  int i = blockIdx.x * 256 + tid;
  if (i < N_NODES){
    int d = deg[i]; if (d > MAXDEG) d = MAXDEG;
    int lpos = atomicAdd(&lh[d], 1);
    perm[pbase[blockIdx.x * (MAXDEG + 1) + d] + lpos] = i;
  }
}

// ---------- all weight tensors: fp32 -> bf16 transposed ----------
__global__ __launch_bounds__(256) void k_cvtW_all(const float* __restrict__ s0, const float* __restrict__ s1,
                                                  const float* __restrict__ s2, const float* __restrict__ s3,
                                                  const float* __restrict__ s4,
                                                  u16* __restrict__ d0, u16* __restrict__ d1,
                                                  u16* __restrict__ d2, u16* __restrict__ d3,
                                                  u16* __restrict__ d4){
  __shared__ float s[32][33];
  int b = blockIdx.x;
  int m = b >> 4, tile = b & 15;
  const float* S; u16* D; int base;
  if (m < 1){ S = s0; D = d0; base = m; }
  else if (m < 9){ S = s1; D = d1; base = m - 1; }
  else if (m < 11){ S = s2; D = d2; base = m - 9; }
  else if (m < 33){ S = s3; D = d3; base = m - 11; }
  else { S = s4; D = d4; base = m - 33; }
  S += (size_t)base * 16384;
  D += (size_t)base * 16384;
  int tr = (tile >> 2) * 32, tc = (tile & 3) * 32;
  int c = threadIdx.x & 31, r0 = threadIdx.x >> 5;
  #pragma unroll
  for (int i = 0; i < 4; ++i){
    int r = r0 + i * 8;
    s[r][c] = S[(size_t)(tr + r) * 128 + tc + c];
  }
  __syncthreads();
  #pragma unroll
  for (int i = 0; i < 4; ++i){
    int r = r0 + i * 8;
    D[(size_t)(tc + r) * 128 + tr + c] = f2bf(s[c][r]);
  }
}

// ---------- x fp32 -> bf16 ----------
__global__ void k_cvtx(const float* __restrict__ x, u16* __restrict__ xb){
  int t = blockIdx.x * 256 + threadIdx.x;
  if (t >= (N_NODES * H_DIM) / 4) return;
  float4 v = ((const float4*)x)[t];
  uint2 o = make_uint2((unsigned)f2bf(v.x) | ((unsigned)f2bf(v.y) << 16),
                       (unsigned)f2bf(v.z) | ((unsigned)f2bf(v.w) << 16));
  ((uint2*)xb)[t] = o;
}

// ---------- RGCN aggregation ----------
__global__ __launch_bounds__(256) void k_rgcn_agg(const u16* __restrict__ hb,
                                                  const int* __restrict__ rel_off,
                                                  const int* __restrict__ row_ptr,
                                                  const int* __restrict__ esrc,
                                                  u16* __restrict__ meanb){
  int node = blockIdx.x * 4 + (threadIdx.x >> 6);
  int lane = threadIdx.x & 63;
  int4 ro = *(const int4*)(rel_off + (size_t)node * 4);
  int nend = row_ptr[node + 1];
  int begs[5] = {ro.x, ro.y, ro.z, ro.w, nend};
  #pragma unroll
  for (int r = 0; r < R_REL; ++r){
    int beg = begs[r], end = begs[r + 1];
    float a0 = 0.f, a1 = 0.f;
    int e = beg;
    for (; e + 4 <= end; e += 4){
      int s0 = esrc[e], s1 = esrc[e + 1], s2 = esrc[e + 2], s3 = esrc[e + 3];
      unsigned v0 = *(const unsigned*)(hb + (size_t)s0 * H_DIM + lane * 2);
      unsigned v1 = *(const unsigned*)(hb + (size_t)s1 * H_DIM + lane * 2);
      unsigned v2 = *(const unsigned*)(hb + (size_t)s2 * H_DIM + lane * 2);
      unsigned v3 = *(const unsigned*)(hb + (size_t)s3 * H_DIM + lane * 2);
      a0 += blo(v0) + blo(v1) + blo(v2) + blo(v3);
      a1 += bhi(v0) + bhi(v1) + bhi(v2) + bhi(v3);
    }
    for (; e < end; ++e){
      unsigned v = *(const unsigned*)(hb + (size_t)esrc[e] * H_DIM + lane * 2);
      a0 += blo(v); a1 += bhi(v);
    }
    int c = end - beg;
    float inv = c > 0 ? 1.f / (float)c : 0.f;
    unsigned o = (unsigned)f2bf(a0 * inv) | ((unsigned)f2bf(a1 * inv) << 16);
    *(unsigned*)(meanb + ((size_t)node * R_REL + r) * H_DIM + lane * 2) = o;
  }
}

// ---------- MFConv aggregation ----------
__global__ __launch_bounds__(256) void k_mf_agg(const u16* __restrict__ hb,
                                                const int* __restrict__ row_ptr,
                                                const int* __restrict__ esrc,
                                                u16* __restrict__ aggb){
  int node = blockIdx.x * 4 + (threadIdx.x >> 6);
  int lane = threadIdx.x & 63;
  int beg = row_ptr[node], end = row_ptr[node + 1];
  float a0 = 0.f, a1 = 0.f;
  int e = beg;
  for (; e + 4 <= end; e += 4){
    int s0 = esrc[e], s1 = esrc[e + 1], s2 = esrc[e + 2], s3 = esrc[e + 3];
    unsigned v0 = *(const unsigned*)(hb + (size_t)s0 * H_DIM + lane * 2);
    unsigned v1 = *(const unsigned*)(hb + (size_t)s1 * H_DIM + lane * 2);
    unsigned v2 = *(const unsigned*)(hb + (size_t)s2 * H_DIM + lane * 2);
    unsigned v3 = *(const unsigned*)(hb + (size_t)s3 * H_DIM + lane * 2);
    a0 += blo(v0) + blo(v1) + blo(v2) + blo(v3);
    a1 += bhi(v0) + bhi(v1) + bhi(v2) + bhi(v3);
  }
  for (; e < end; ++e){
    unsigned v = *(const unsigned*)(hb + (size_t)esrc[e] * H_DIM + lane * 2);
    a0 += blo(v); a1 += bhi(v);
  }
  unsigned o = (unsigned)f2bf(a0) | ((unsigned)f2bf(a1) << 16);
  *(unsigned*)(aggb + (size_t)node * H_DIM + lane * 2) = o;
}

// ---------- gemm0: wave = 16 cols x 64 rows, B-frags in registers ----------
__global__ __launch_bounds__(256) void k_gemm0(const u16* __restrict__ xb, const u16* __restrict__ wt,
                                               const float* __restrict__ bias, u16* __restrict__ hbo){
  int wid = blockIdx.x * 4 + (threadIdx.x >> 6);
  int lane = threadIdx.x & 63;
  int ct = wid & 7;
  int m0 = (wid >> 3) * 64;
  int arow = lane & 15, kg = lane >> 4;
  int col = ct * 16 + arow;
  f32x4 acc[4];
  #pragma unroll
  for (int rt = 0; rt < 4; ++rt) acc[rt] = (f32x4){0.f, 0.f, 0.f, 0.f};
  bf16x8 b[4];
  #pragma unroll
  for (int kk = 0; kk < 4; ++kk)
    b[kk] = *(const bf16x8*)(wt + (size_t)col * F_IN + kk * 32 + kg * 8);
  #pragma unroll
  for (int rt = 0; rt < 4; ++rt){
    const u16* Arow = xb + (size_t)(m0 + rt * 16 + arow) * F_IN;
    #pragma unroll
    for (int kk = 0; kk < 4; ++kk){
      bf16x8 a = *(const bf16x8*)(Arow + kk * 32 + kg * 8);
      acc[rt] = __builtin_amdgcn_mfma_f32_16x16x32_bf16(a, b[kk], acc[rt], 0, 0, 0);
    }
  }
  float bb = bias[col];
  #pragma unroll
  for (int rt = 0; rt < 4; ++rt)
    #pragma unroll
    for (int j = 0; j < 4; ++j){
      int gr = m0 + rt * 16 + kg * 4 + j;
      hbo[(size_t)gr * H_DIM + col] = f2bf(relu_f(acc[rt][j] + bb));
    }
}

// ---------- RGCN GEMM: wave = 16 cols x 64 rows, K = 5*128, B per seg in regs ----------
__global__ __launch_bounds__(256) void k_rgcn_gemm(const u16* __restrict__ meanb, const u16* __restrict__ hb,
                                                   const u16* __restrict__ wrel, const u16* __restrict__ wroot,
                                                   const float* __restrict__ bias, u16* __restrict__ hbo){
  int wid = blockIdx.x * 4 + (threadIdx.x >> 6);
  int lane = threadIdx.x & 63;
  int ct = wid & 7;
  int m0 = (wid >> 3) * 64;
  int arow = lane & 15, kg = lane >> 4;
  int col = ct * 16 + arow;
  f32x4 acc[4];
  #pragma unroll
  for (int rt = 0; rt < 4; ++rt) acc[rt] = (f32x4){0.f, 0.f, 0.f, 0.f};
  #pragma unroll
  for (int seg = 0; seg < 5; ++seg){
    const u16* WT = (seg < 4) ? wrel + (size_t)seg * 16384 : wroot;
    bf16x8 b[4];
    #pragma unroll
    for (int kk = 0; kk < 4; ++kk)
      b[kk] = *(const bf16x8*)(WT + (size_t)col * H_DIM + kk * 32 + kg * 8);
    #pragma unroll
    for (int rt = 0; rt < 4; ++rt){
      int row = m0 + rt * 16 + arow;
      const u16* Arow = (seg < 4) ? meanb + ((size_t)row * R_REL + seg) * H_DIM
                                  : hb + (size_t)row * H_DIM;
      #pragma unroll
      for (int kk = 0; kk < 4; ++kk){
        bf16x8 a = *(const bf16x8*)(Arow + kk * 32 + kg * 8);
        acc[rt] = __builtin_amdgcn_mfma_f32_16x16x32_bf16(a, b[kk], acc[rt], 0, 0, 0);
      }
    }
  }
  float bb = bias[col];
  #pragma unroll
  for (int rt = 0; rt < 4; ++rt)
    #pragma unroll
    for (int j = 0; j < 4; ++j){
      int gr = m0 + rt * 16 + kg * 4 + j;
      hbo[(size_t)gr * H_DIM + col] = f2bf(relu_f(acc[rt][j] + bb));
    }
}

// ---------- MFConv GEMM: wave = 16 cols x 64 bucket rows ----------
template<int FINAL>
__global__ __launch_bounds__(256) void k_mf_gemm(const u16* __restrict__ aggb, const u16* __restrict__ hb,
                                                 const u16* __restrict__ wl, const u16* __restrict__ wr,
                                                 const float* __restrict__ bl,
                                                 const int* __restrict__ bcount, const int* __restrict__ boff,
                                                 const int* __restrict__ perm,
                                                 u16* __restrict__ hbo, float* __restrict__ hf){
  int wid = blockIdx.x * 4 + (threadIdx.x >> 6);
  int lane = threadIdx.x & 63;
  int w = wid;
  int d = -1, tile = 0, ct = 0;
  for (int dd = 0; dd <= MAXDEG; ++dd){
    int tot = ((bcount[dd] + 63) >> 6) << 3;
    if (w < tot){ d = dd; tile = w >> 3; ct = w & 7; break; }
    w -= tot;
  }
  int nrows = 0, start = 0;
  if (d < 0){ d = 0; }
  else {
    int cnt_d = bcount[d];
    start = boff[d] + tile * 64;
    nrows = cnt_d - tile * 64; if (nrows > 64) nrows = 64;
  }
  int arow = lane & 15, kg = lane >> 4;
  int col = ct * 16 + arow;
  f32x4 acc[4];
  #pragma unroll
  for (int rt = 0; rt < 4; ++rt) acc[rt] = (f32x4){0.f, 0.f, 0.f, 0.f};
  int ar[4];
  #pragma unroll
  for (int rt = 0; rt < 4; ++rt){
    int idx = rt * 16 + arow;
    ar[rt] = (idx < nrows) ? perm[start + idx] : -1;
  }
  bf16x8 zf = {0, 0, 0, 0, 0, 0, 0, 0};
  #pragma unroll
  for (int seg = 0; seg < 2; ++seg){
    const u16* Abase = seg ? hb : aggb;
    const u16* WT = (seg ? wr : wl) + (size_t)d * 16384;
    bf16x8 b[4];
    #pragma unroll
    for (int kk = 0; kk < 4; ++kk)
      b[kk] = *(const bf16x8*)(WT + (size_t)col * H_DIM + kk * 32 + kg * 8);
    #pragma unroll
    for (int rt = 0; rt < 4; ++rt){
      int row = ar[rt];
      const u16* Arow = Abase + (size_t)(row < 0 ? 0 : row) * H_DIM;
      #pragma unroll
      for (int kk = 0; kk < 4; ++kk){
        bf16x8 a = (row >= 0) ? *(const bf16x8*)(Arow + kk * 32 + kg * 8) : zf;
        acc[rt] = __builtin_amdgcn_mfma_f32_16x16x32_bf16(a, b[kk], acc[rt], 0, 0, 0);
      }
    }
  }
  float bb = bl[(size_t)d * H_DIM + col];
  #pragma unroll
  for (int rt = 0; rt < 4; ++rt)
    #pragma unroll
    for (int j = 0; j < 4; ++j){
      int idx = rt * 16 + kg * 4 + j;
      int gr = (idx < nrows) ? perm[start + idx] : -1;
      if (gr >= 0){
        float v = acc[rt][j] + bb;
        if (FINAL) hf[(size_t)gr * H_DIM + col] = v;
        else       hbo[(size_t)gr * H_DIM + col] = f2bf(relu_f(v));
      }
    }
}

// ---------- graph boundaries ----------
__global__ void k_goff(const int* __restrict__ batch, int* __restrict__ goff){
  int n = blockIdx.x * blockDim.x + threadIdx.x;
  if (n >= N_NODES) return;
  int b = batch[n];
  int bp = (n == 0) ? -1 : batch[n - 1];
  for (int g = bp + 1; g <= b; ++g) goff[g] = n;
  if (n == N_NODES - 1){
    for (int g = b + 1; g <= G_GRAPHS; ++g) goff[g] = N_NODES;
  }
}

// ---------- pooling ----------
__global__ __launch_bounds__(256) void k_pool(const float* __restrict__ h, const int* __restrict__ goff,
                                              float* __restrict__ pooled){
  __shared__ float4 sred[8][32];
  int g = blockIdx.x;
  int tid = threadIdx.x;
  int rg = tid >> 5, lane = tid & 31;
  int beg = goff[g], end = goff[g + 1];
  float4 acc = make_float4(0.f, 0.f, 0.f, 0.f);
  for (int n = beg + rg; n < end; n += 8){
    float4 v = ((const float4*)(h + (size_t)n * H_DIM))[lane];
    acc.x += v.x; acc.y += v.y; acc.z += v.z; acc.w += v.w;
  }
  sred[rg][lane] = acc;
  __syncthreads();
  if (tid < 32){
    float4 s = sred[0][tid];
    #pragma unroll
    for (int r = 1; r < 8; ++r){
      float4 v = sred[r][tid];
      s.x += v.x; s.y += v.y; s.z += v.z; s.w += v.w;
    }
    *(float4*)(pooled + (size_t)g * H_DIM + tid * 4) = s;
  }
}

// ---------- MLP ----------
__global__ void k_mlp1(const float* __restrict__ pooled, const float* __restrict__ W1,
                       const float* __restrict__ b1, float* __restrict__ T){
  int t = blockIdx.x * blockDim.x + threadIdx.x;
  if (t >= G_GRAPHS * H_DIM) return;
  int n = t >> 7, j = t & 127;
  float s = b1[j];
  for (int k = 0; k < H_DIM; ++k) s += pooled[n * H_DIM + k] * W1[k * H_DIM + j];
  T[t] = relu_f(s);
}

__global__ void k_mlp2(const float* __restrict__ T, const float* __restrict__ W2,
                       const float* __restrict__ b2, float* __restrict__ out){
  int t = blockIdx.x * blockDim.x + threadIdx.x;
  if (t >= G_GRAPHS * N_OUT) return;
  int n = t / N_OUT, j = t - n * N_OUT;
  float s = b2[j];
  for (int k = 0; k < H_DIM; ++k) s += T[n * H_DIM + k] * W2[k * N_OUT + j];
  out[t] = s;
}

extern "C" void kernel_launch(void* const* d_in, const int* in_sizes, int n_in,
                              void* d_out, int out_size, void* d_ws, size_t ws_size,
                              hipStream_t stream){
  const float* x      = (const float*)d_in[0];
  const int*   ei     = (const int*)d_in[1];
  const int*   ea     = (const int*)d_in[2];
  const int*   batch  = (const int*)d_in[3];
  const float* W0     = (const float*)d_in[4];
  const float* b0     = (const float*)d_in[5];
  const float* rWrel  = (const float*)d_in[6];
  const float* rWroot = (const float*)d_in[7];
  const float* rb     = (const float*)d_in[8];
  const float* mWl    = (const float*)d_in[9];
  const float* mbl    = (const float*)d_in[10];
  const float* mWr    = (const float*)d_in[11];
  const float* W1     = (const float*)d_in[12];
  const float* b1     = (const float*)d_in[13];
  const float* W2     = (const float*)d_in[14];
  const float* b2     = (const float*)d_in[15];
  float* out = (float*)d_out;

  const int* src = ei;
  const int* dst = ei + N_EDGES;

  char* ws = (char*)d_ws;
  size_t off = 0;
  auto alloc = [&](size_t bytes) -> void* {
    void* p = ws + off;
    off += (bytes + 255) & ~(size_t)255;
    return p;
  };
  u16* xb      = (u16*)alloc((size_t)N_NODES * H_DIM * 2);
  u16* hbA     = (u16*)alloc((size_t)N_NODES * H_DIM * 2);
  u16* hbB     = (u16*)alloc((size_t)N_NODES * H_DIM * 2);
  u16* meanb   = (u16*)alloc((size_t)N_NODES * R_REL * H_DIM * 2);
  u16* aggb    = meanb;  // reuse
  float* hf    = (float*)alloc((size_t)N_NODES * H_DIM * 4);
  u16* wt0     = (u16*)alloc((size_t)1 * 16384 * 2);
  u16* wtRel   = (u16*)alloc((size_t)NBLK * R_REL * 16384 * 2);
  u16* wtRoot  = (u16*)alloc((size_t)NBLK * 16384 * 2);
  u16* wtWl    = (u16*)alloc((size_t)NBLK * (MAXDEG + 1) * 16384 * 2);
  u16* wtWr    = (u16*)alloc((size_t)NBLK * (MAXDEG + 1) * 16384 * 2);
  float* pooled = (float*)alloc((size_t)G_GRAPHS * H_DIM * 4);
  float* T      = (float*)alloc((size_t)G_GRAPHS * H_DIM * 4);
  int* cnt4     = (int*)alloc((size_t)N_NODES * R_REL * 4);
  int* deg      = (int*)alloc((size_t)N_NODES * 4);
  int* row_ptr  = (int*)alloc((size_t)(N_NODES + 1) * 4);
  int* rel_off  = (int*)alloc((size_t)N_NODES * R_REL * 4);
  int* cursor   = (int*)alloc((size_t)N_NODES * R_REL * 4);
  int* esrc     = (int*)alloc((size_t)N_EDGES * 4);
  int* bsum     = (int*)alloc((size_t)NSCAN_BLK * 4);
  int* bbase    = (int*)alloc((size_t)NSCAN_BLK * 4);
  int* bhist    = (int*)alloc((size_t)NSCAN_BLK * (MAXDEG + 1) * 4);
  int* pbase    = (int*)alloc((size_t)NSCAN_BLK * (MAXDEG + 1) * 4);
  int* perm     = (int*)alloc((size_t)N_NODES * 4);
  int* bcount   = (int*)alloc(16 * 4);
  int* boff     = (int*)alloc(16 * 4);
  int* goff     = (int*)alloc((size_t)(G_GRAPHS + 1) * 4);

  hipMemsetAsync(cnt4, 0, (size_t)N_NODES * R_REL * 4, stream);
  hipMemsetAsync(cursor, 0, (size_t)N_NODES * R_REL * 4, stream);

  // graph structure
  k_cnt<<<(N_EDGES + 255) / 256, 256, 0, stream>>>(dst, ea, cnt4);
  k_scan_a<<<NSCAN_BLK, 256, 0, stream>>>(cnt4, deg, row_ptr, bsum, bhist);
  k_scan_b<<<1, 256, 0, stream>>>(bsum, bbase);
  k_scan_c<<<NSCAN_BLK, 256, 0, stream>>>(row_ptr, bbase, cnt4, rel_off);
  k_csr_fill<<<(N_EDGES + 255) / 256, 256, 0, stream>>>(src, dst, ea, rel_off, cursor, esrc);
  k_bscan<<<1, 64, 0, stream>>>(bhist, pbase, bcount, boff);
  k_bfill<<<NSCAN_BLK, 256, 0, stream>>>(deg, pbase, perm);
  k_goff<<<(N_NODES + 255) / 256, 256, 0, stream>>>(batch, goff);

  // weight + input conversion
  k_cvtW_all<<<55 * 16, 256, 0, stream>>>(W0, rWrel, rWroot, mWl, mWr,
                                          wt0, wtRel, wtRoot, wtWl, wtWr);
  k_cvtx<<<(N_NODES * H_DIM / 4 + 255) / 256, 256, 0, stream>>>(x, xb);

  // 5000 waves: (625 row-chunks of 64) x 8 col-tiles
  k_gemm0<<<1250, 256, 0, stream>>>(xb, wt0, b0, hbA);

  u16* hin = hbA;
  u16* hout = hbB;
  for (int blk = 0; blk < NBLK; ++blk){
    k_rgcn_agg<<<N_NODES / 4, 256, 0, stream>>>(hin, rel_off, row_ptr, esrc, meanb);
    k_rgcn_gemm<<<1250, 256, 0, stream>>>(meanb, hin,
        wtRel + (size_t)blk * R_REL * 16384,
        wtRoot + (size_t)blk * 16384,
        rb + (size_t)blk * H_DIM, hout);
    { u16* tmp = hin; hin = hout; hout = tmp; }

    k_mf_agg<<<N_NODES / 4, 256, 0, stream>>>(hin, row_ptr, esrc, aggb);
    const u16* wl_b = wtWl + (size_t)blk * (MAXDEG + 1) * 16384;
    const u16* wr_b = wtWr + (size_t)blk * (MAXDEG + 1) * 16384;
    const float* bl_b = mbl + (size_t)blk * (MAXDEG + 1) * H_DIM;
    int grid_mf = ((N_NODES / 64 + MAXDEG + 1) * 8 + 3) / 4;   // 1272
    if (blk == NBLK - 1)
      k_mf_gemm<1><<<grid_mf, 256, 0, stream>>>(aggb, hin, wl_b, wr_b, bl_b,
                                                bcount, boff, perm, hout, hf);
    else
      k_mf_gemm<0><<<grid_mf, 256, 0, stream>>>(aggb, hin, wl_b, wr_b, bl_b,
                                                bcount, boff, perm, hout, hf);
    { u16* tmp = hin; hin = hout; hout = tmp; }
  }

  k_pool<<<G_GRAPHS, 256, 0, stream>>>(hf, goff, pooled);
  k_mlp1<<<(G_GRAPHS * H_DIM + 255) / 256, 256, 0, stream>>>(pooled, W1, b1, T);
  k_mlp2<<<(G_GRAPHS * N_OUT + 255) / 256, 256, 0, stream>>>(T, W2, b2, out);
}

// Round 6
// 400.503 us; speedup vs baseline: 14.4980x; 1.2114x over previous
//
#include <hip/hip_runtime.h>
#include <hip/hip_bf16.h>

#define N_NODES 40000
#define N_EDGES 640000
#define R_REL 4
#define F_IN 128
#define H_DIM 128
#define NBLK 2
#define G_GRAPHS 64
#define N_OUT 10
#define MAXDEG 10
#define NSCAN_BLK ((N_NODES + 255) / 256)   // 157

typedef unsigned short u16;
typedef float f32x4 __attribute__((ext_vector_type(4)));
typedef short bf16x8 __attribute__((ext_vector_type(8)));

__device__ __forceinline__ float relu_f(float x){ return x > 0.f ? x : 0.f; }

// fp32 -> bf16 round-to-nearest-even
__device__ __forceinline__ u16 f2bf(float f){
  union { float f; unsigned int u; } v; v.f = f;
  unsigned int r = v.u + 0x7fffu + ((v.u >> 16) & 1u);
  return (u16)(r >> 16);
}
__device__ __forceinline__ float b2f(u16 u){
  union { unsigned int u; float f; } v; v.u = ((unsigned int)u) << 16; return v.f;
}
__device__ __forceinline__ float blo(unsigned v){ return b2f((u16)v); }
__device__ __forceinline__ float bhi(unsigned v){ return b2f((u16)(v >> 16)); }

// async global->LDS 16B: LDS dest is wave-uniform base + lane*16 (linear);
// per-lane global src carries the inverse swizzle (rule #21).
__device__ __forceinline__ void gload16(const void* g, void* l){
  __builtin_amdgcn_global_load_lds(
      (const __attribute__((address_space(1))) void*)g,
      (__attribute__((address_space(3))) void*)l, 16, 0, 0);
}

// ---------- per-(node,rel) counts ----------
__global__ void k_cnt(const int* __restrict__ dst, const int* __restrict__ et, int* __restrict__ cnt4){
  int e = blockIdx.x * blockDim.x + threadIdx.x;
  if (e >= N_EDGES) return;
  atomicAdd(&cnt4[dst[e] * R_REL + et[e]], 1);
}

// ---------- scan A ----------
__global__ __launch_bounds__(256) void k_scan_a(const int* __restrict__ cnt4, int* __restrict__ deg,
                                                int* __restrict__ row_ptr, int* __restrict__ bsum,
                                                int* __restrict__ bhist){
  __shared__ int s[256];
  __shared__ int lh[16];
  int tid = threadIdx.x;
  int i = blockIdx.x * 256 + tid;
  if (tid < 16) lh[tid] = 0;
  int d = 0;
  if (i < N_NODES){
    int4 c = *(const int4*)(cnt4 + (size_t)i * 4);
    d = c.x + c.y + c.z + c.w;
    deg[i] = d;
  }
  s[tid] = d;
  __syncthreads();
  if (i < N_NODES){
    int dc = d > MAXDEG ? MAXDEG : d;
    atomicAdd(&lh[dc], 1);
  }
  for (int o = 1; o < 256; o <<= 1){
    int t = (tid >= o) ? s[tid - o] : 0;
    __syncthreads();
    s[tid] += t;
    __syncthreads();
  }
  if (i < N_NODES) row_ptr[i] = s[tid] - d;
  if (tid == 255) bsum[blockIdx.x] = s[255];
  if (tid <= MAXDEG) bhist[blockIdx.x * (MAXDEG + 1) + tid] = lh[tid];
}

__global__ __launch_bounds__(256) void k_scan_b(int* __restrict__ bsum, int* __restrict__ bbase){
  __shared__ int s[256];
  int tid = threadIdx.x;
  int v = (tid < NSCAN_BLK) ? bsum[tid] : 0;
  s[tid] = v;
  __syncthreads();
  for (int o = 1; o < 256; o <<= 1){
    int t = (tid >= o) ? s[tid - o] : 0;
    __syncthreads();
    s[tid] += t;
    __syncthreads();
  }
  if (tid < NSCAN_BLK) bbase[tid] = s[tid] - v;
}

__global__ __launch_bounds__(256) void k_scan_c(int* __restrict__ row_ptr, const int* __restrict__ bbase,
                                                const int* __restrict__ cnt4, int* __restrict__ rel_off){
  int i = blockIdx.x * 256 + threadIdx.x;
  if (i < N_NODES){
    int base = row_ptr[i] + bbase[blockIdx.x];
    row_ptr[i] = base;
    int4 c = *(const int4*)(cnt4 + (size_t)i * 4);
    int4 o;
    o.x = base;
    o.y = base + c.x;
    o.z = o.y + c.y;
    o.w = o.z + c.z;
    *(int4*)(rel_off + (size_t)i * 4) = o;
  }
  if (i == 0) row_ptr[N_NODES] = N_EDGES;
}

// ---------- CSR fill ----------
__global__ void k_csr_fill(const int* __restrict__ src, const int* __restrict__ dst,
                           const int* __restrict__ et, const int* __restrict__ rel_off,
                           int* __restrict__ cursor, int* __restrict__ esrc){
  int e = blockIdx.x * blockDim.x + threadIdx.x;
  if (e >= N_EDGES) return;
  int cell = dst[e] * R_REL + et[e];
  int p = atomicAdd(&cursor[cell], 1);
  esrc[rel_off[cell] + p] = src[e];
}

// ---------- degree-bucket counting sort ----------
__global__ __launch_bounds__(64) void k_bscan(const int* __restrict__ bhist, int* __restrict__ pbase,
                                              int* __restrict__ bcount, int* __restrict__ boff){
  __shared__ int cnt_s[MAXDEG + 1];
  __shared__ int off_s[MAXDEG + 1];
  int d = threadIdx.x;
  if (d <= MAXDEG){
    int run = 0;
    for (int b = 0; b < NSCAN_BLK; ++b){
      pbase[b * (MAXDEG + 1) + d] = run;
      run += bhist[b * (MAXDEG + 1) + d];
    }
    cnt_s[d] = run;
    bcount[d] = run;
  }
  __syncthreads();
  if (d == 0){
    int s = 0;
    for (int dd = 0; dd <= MAXDEG; ++dd){ off_s[dd] = s; boff[dd] = s; s += cnt_s[dd]; }
  }
  __syncthreads();
  if (d <= MAXDEG){
    int base = off_s[d];
    for (int b = 0; b < NSCAN_BLK; ++b) pbase[b * (MAXDEG + 1) + d] += base;
  }
}

__global__ __launch_bounds__(256) void k_bfill(const int* __restrict__ deg, const int* __restrict__ pbase,
                                               int* __restrict__ perm){
  __shared__ int lh[MAXDEG + 1];
  int tid = threadIdx.x;
  if (tid <= MAXDEG) lh[tid] = 0;
  __syncthreads();
  int i = blockIdx.x * 256 + tid;
  if (i < N_NODES){
    int d = deg[i]; if (d > MAXDEG) d = MAXDEG;
    int lpos = atomicAdd(&lh[d], 1);
    perm[pbase[blockIdx.x * (MAXDEG + 1) + d] + lpos] = i;
  }
}

// ---------- all weight tensors: fp32 -> bf16 transposed ----------
__global__ __launch_bounds__(256) void k_cvtW_all(const float* __restrict__ s0, const float* __restrict__ s1,
                                                  const float* __restrict__ s2, const float* __restrict__ s3,
                                                  const float* __restrict__ s4,
                                                  u16* __restrict__ d0, u16* __restrict__ d1,
                                                  u16* __restrict__ d2, u16* __restrict__ d3,
                                                  u16* __restrict__ d4){
  __shared__ float s[32][33];
  int b = blockIdx.x;
  int m = b >> 4, tile = b & 15;
  const float* S; u16* D; int base;
  if (m < 1){ S = s0; D = d0; base = m; }
  else if (m < 9){ S = s1; D = d1; base = m - 1; }
  else if (m < 11){ S = s2; D = d2; base = m - 9; }
  else if (m < 33){ S = s3; D = d3; base = m - 11; }
  else { S = s4; D = d4; base = m - 33; }
  S += (size_t)base * 16384;
  D += (size_t)base * 16384;
  int tr = (tile >> 2) * 32, tc = (tile & 3) * 32;
  int c = threadIdx.x & 31, r0 = threadIdx.x >> 5;
  #pragma unroll
  for (int i = 0; i < 4; ++i){
    int r = r0 + i * 8;
    s[r][c] = S[(size_t)(tr + r) * 128 + tc + c];
  }
  __syncthreads();
  #pragma unroll
  for (int i = 0; i < 4; ++i){
    int r = r0 + i * 8;
    D[(size_t)(tc + r) * 128 + tr + c] = f2bf(s[c][r]);
  }
}

// ---------- x fp32 -> bf16 ----------
__global__ void k_cvtx(const float* __restrict__ x, u16* __restrict__ xb){
  int t = blockIdx.x * 256 + threadIdx.x;
  if (t >= (N_NODES * H_DIM) / 4) return;
  float4 v = ((const float4*)x)[t];
  uint2 o = make_uint2((unsigned)f2bf(v.x) | ((unsigned)f2bf(v.y) << 16),
                       (unsigned)f2bf(v.z) | ((unsigned)f2bf(v.w) << 16));
  ((uint2*)xb)[t] = o;
}

// ---------- RGCN aggregation ----------
__global__ __launch_bounds__(256) void k_rgcn_agg(const u16* __restrict__ hb,
                                                  const int* __restrict__ rel_off,
                                                  const int* __restrict__ row_ptr,
                                                  const int* __restrict__ esrc,
                                                  u16* __restrict__ meanb){
  int node = blockIdx.x * 4 + (threadIdx.x >> 6);
  int lane = threadIdx.x & 63;
  int4 ro = *(const int4*)(rel_off + (size_t)node * 4);
  int nend = row_ptr[node + 1];
  int begs[5] = {ro.x, ro.y, ro.z, ro.w, nend};
  #pragma unroll
  for (int r = 0; r < R_REL; ++r){
    int beg = begs[r], end = begs[r + 1];
    float a0 = 0.f, a1 = 0.f;
    int e = beg;
    for (; e + 4 <= end; e += 4){
      int s0 = esrc[e], s1 = esrc[e + 1], s2 = esrc[e + 2], s3 = esrc[e + 3];
      unsigned v0 = *(const unsigned*)(hb + (size_t)s0 * H_DIM + lane * 2);
      unsigned v1 = *(const unsigned*)(hb + (size_t)s1 * H_DIM + lane * 2);
      unsigned v2 = *(const unsigned*)(hb + (size_t)s2 * H_DIM + lane * 2);
      unsigned v3 = *(const unsigned*)(hb + (size_t)s3 * H_DIM + lane * 2);
      a0 += blo(v0) + blo(v1) + blo(v2) + blo(v3);
      a1 += bhi(v0) + bhi(v1) + bhi(v2) + bhi(v3);
    }
    for (; e < end; ++e){
      unsigned v = *(const unsigned*)(hb + (size_t)esrc[e] * H_DIM + lane * 2);
      a0 += blo(v); a1 += bhi(v);
    }
    int c = end - beg;
    float inv = c > 0 ? 1.f / (float)c : 0.f;
    unsigned o = (unsigned)f2bf(a0 * inv) | ((unsigned)f2bf(a1 * inv) << 16);
    *(unsigned*)(meanb + ((size_t)node * R_REL + r) * H_DIM + lane * 2) = o;
  }
}

// ---------- MFConv aggregation ----------
__global__ __launch_bounds__(256) void k_mf_agg(const u16* __restrict__ hb,
                                                const int* __restrict__ row_ptr,
                                                const int* __restrict__ esrc,
                                                u16* __restrict__ aggb){
  int node = blockIdx.x * 4 + (threadIdx.x >> 6);
  int lane = threadIdx.x & 63;
  int beg = row_ptr[node], end = row_ptr[node + 1];
  float a0 = 0.f, a1 = 0.f;
  int e = beg;
  for (; e + 4 <= end; e += 4){
    int s0 = esrc[e], s1 = esrc[e + 1], s2 = esrc[e + 2], s3 = esrc[e + 3];
    unsigned v0 = *(const unsigned*)(hb + (size_t)s0 * H_DIM + lane * 2);
    unsigned v1 = *(const unsigned*)(hb + (size_t)s1 * H_DIM + lane * 2);
    unsigned v2 = *(const unsigned*)(hb + (size_t)s2 * H_DIM + lane * 2);
    unsigned v3 = *(const unsigned*)(hb + (size_t)s3 * H_DIM + lane * 2);
    a0 += blo(v0) + blo(v1) + blo(v2) + blo(v3);
    a1 += bhi(v0) + bhi(v1) + bhi(v2) + bhi(v3);
  }
  for (; e < end; ++e){
    unsigned v = *(const unsigned*)(hb + (size_t)esrc[e] * H_DIM + lane * 2);
    a0 += blo(v); a1 += bhi(v);
  }
  unsigned o = (unsigned)f2bf(a0) | ((unsigned)f2bf(a1) << 16);
  *(unsigned*)(aggb + (size_t)node * H_DIM + lane * 2) = o;
}

// ======== LDS-staged MFMA GEMMs ========
// Tile: 32 rows x 128 cols, 512 threads (8 waves), wave w = col-tile w.
// A staged to LDS via global_load_lds(16B): linear dest, XOR-swizzled source col.
// Read with same swizzle: byte ^= ((row&7)<<4)  -> ds_read_b128 conflict-floor.

// ---------- gemm0: hb = bf16(relu(xb @ W0T + b0)), K=128 ----------
__global__ __launch_bounds__(512) void k_gemm0(const u16* __restrict__ xb, const u16* __restrict__ wt,
                                               const float* __restrict__ bias, u16* __restrict__ hbo){
  __shared__ u16 lds[32][128];
  int tid = threadIdx.x;
  int w = tid >> 6, lane = tid & 63;
  int m0 = blockIdx.x * 32;
  int rg = lane >> 4, cb = (lane & 15) << 4;
  int srow = w * 4 + rg;
  int swcb = cb ^ ((srow & 7) << 4);
  gload16(xb + (size_t)(m0 + srow) * F_IN + (swcb >> 1), &lds[w * 4][0]);
  __syncthreads();

  int arow = lane & 15, kg = lane >> 4;
  int col = w * 16 + arow;
  f32x4 acc[2];
  acc[0] = (f32x4){0.f, 0.f, 0.f, 0.f};
  acc[1] = (f32x4){0.f, 0.f, 0.f, 0.f};
  bf16x8 b[4];
  #pragma unroll
  for (int kk = 0; kk < 4; ++kk)
    b[kk] = *(const bf16x8*)(wt + (size_t)col * F_IN + kk * 32 + kg * 8);
  #pragma unroll
  for (int rt = 0; rt < 2; ++rt){
    int row = rt * 16 + arow;
    const char* base = (const char*)&lds[0][0] + row * 256;
    int sx = (row & 7) << 4;
    #pragma unroll
    for (int kk = 0; kk < 4; ++kk){
      bf16x8 a = *(const bf16x8*)(base + ((kk * 64 + kg * 16) ^ sx));
      acc[rt] = __builtin_amdgcn_mfma_f32_16x16x32_bf16(a, b[kk], acc[rt], 0, 0, 0);
    }
  }
  float bb = bias[col];
  #pragma unroll
  for (int rt = 0; rt < 2; ++rt)
    #pragma unroll
    for (int j = 0; j < 4; ++j){
      int gr = m0 + rt * 16 + kg * 4 + j;
      hbo[(size_t)gr * H_DIM + col] = f2bf(relu_f(acc[rt][j] + bb));
    }
}

// ---------- RGCN GEMM: K = 5*128 (4 relation means + root), all segs staged upfront ----------
__global__ __launch_bounds__(512) void k_rgcn_gemm(const u16* __restrict__ meanb, const u16* __restrict__ hb,
                                                   const u16* __restrict__ wrel, const u16* __restrict__ wroot,
                                                   const float* __restrict__ bias, u16* __restrict__ hbo){
  __shared__ u16 lds[5][32][128];   // 40 KB
  int tid = threadIdx.x;
  int w = tid >> 6, lane = tid & 63;
  int m0 = blockIdx.x * 32;
  int rg = lane >> 4, cb = (lane & 15) << 4;
  int srow = w * 4 + rg;
  int swcb = cb ^ ((srow & 7) << 4);
  #pragma unroll
  for (int s = 0; s < 4; ++s)
    gload16(meanb + ((size_t)(m0 + srow) * R_REL + s) * H_DIM + (swcb >> 1), &lds[s][w * 4][0]);
  gload16(hb + (size_t)(m0 + srow) * H_DIM + (swcb >> 1), &lds[4][w * 4][0]);
  __syncthreads();

  int arow = lane & 15, kg = lane >> 4;
  int col = w * 16 + arow;
  f32x4 acc[2];
  acc[0] = (f32x4){0.f, 0.f, 0.f, 0.f};
  acc[1] = (f32x4){0.f, 0.f, 0.f, 0.f};
  #pragma unroll
  for (int s = 0; s < 5; ++s){
    const u16* WT = (s < 4) ? wrel + (size_t)s * 16384 : wroot;
    bf16x8 b[4];
    #pragma unroll
    for (int kk = 0; kk < 4; ++kk)
      b[kk] = *(const bf16x8*)(WT + (size_t)col * H_DIM + kk * 32 + kg * 8);
    #pragma unroll
    for (int rt = 0; rt < 2; ++rt){
      int row = rt * 16 + arow;
      const char* base = (const char*)&lds[s][0][0] + row * 256;
      int sx = (row & 7) << 4;
      #pragma unroll
      for (int kk = 0; kk < 4; ++kk){
        bf16x8 a = *(const bf16x8*)(base + ((kk * 64 + kg * 16) ^ sx));
        acc[rt] = __builtin_amdgcn_mfma_f32_16x16x32_bf16(a, b[kk], acc[rt], 0, 0, 0);
      }
    }
  }
  float bb = bias[col];
  #pragma unroll
  for (int rt = 0; rt < 2; ++rt)
    #pragma unroll
    for (int j = 0; j < 4; ++j){
      int gr = m0 + rt * 16 + kg * 4 + j;
      hbo[(size_t)gr * H_DIM + col] = f2bf(relu_f(acc[rt][j] + bb));
    }
}

// ---------- MFConv GEMM: per-degree buckets, gathered rows staged to LDS ----------
template<int FINAL>
__global__ __launch_bounds__(512) void k_mf_gemm(const u16* __restrict__ aggb, const u16* __restrict__ hb,
                                                 const u16* __restrict__ wl, const u16* __restrict__ wr,
                                                 const float* __restrict__ bl,
                                                 const int* __restrict__ bcount, const int* __restrict__ boff,
                                                 const int* __restrict__ perm,
                                                 u16* __restrict__ hbo, float* __restrict__ hf){
  __shared__ u16 lds[2][32][128];   // 16 KB
  __shared__ int rows_s[32];
  int t = blockIdx.x;
  int d = -1, tile = 0;
  for (int dd = 0; dd <= MAXDEG; ++dd){
    int nt = (bcount[dd] + 31) >> 5;
    if (t < nt){ d = dd; tile = t; break; }
    t -= nt;
  }
  if (d < 0) return;
  int cnt_d = bcount[d];
  int start = boff[d] + tile * 32;
  int nrows = cnt_d - tile * 32; if (nrows > 32) nrows = 32;

  int tid = threadIdx.x;
  int w = tid >> 6, lane = tid & 63;
  if (tid < 32) rows_s[tid] = (tid < nrows) ? perm[start + tid] : -1;

  int rg = lane >> 4, cb = (lane & 15) << 4;
  int srow = w * 4 + rg;
  int swcb = cb ^ ((srow & 7) << 4);
  int node = perm[start + (srow < nrows ? srow : 0)];
  gload16(aggb + (size_t)node * H_DIM + (swcb >> 1), &lds[0][w * 4][0]);
  gload16(hb   + (size_t)node * H_DIM + (swcb >> 1), &lds[1][w * 4][0]);
  __syncthreads();

  int arow = lane & 15, kg = lane >> 4;
  int col = w * 16 + arow;
  f32x4 acc[2];
  acc[0] = (f32x4){0.f, 0.f, 0.f, 0.f};
  acc[1] = (f32x4){0.f, 0.f, 0.f, 0.f};
  #pragma unroll
  for (int s = 0; s < 2; ++s){
    const u16* WT = (s ? wr : wl) + (size_t)d * 16384;
    bf16x8 b[4];
    #pragma unroll
    for (int kk = 0; kk < 4; ++kk)
      b[kk] = *(const bf16x8*)(WT + (size_t)col * H_DIM + kk * 32 + kg * 8);
    #pragma unroll
    for (int rt = 0; rt < 2; ++rt){
      int row = rt * 16 + arow;
      const char* base = (const char*)&lds[s][0][0] + row * 256;
      int sx = (row & 7) << 4;
      #pragma unroll
      for (int kk = 0; kk < 4; ++kk){
        bf16x8 a = *(const bf16x8*)(base + ((kk * 64 + kg * 16) ^ sx));
        acc[rt] = __builtin_amdgcn_mfma_f32_16x16x32_bf16(a, b[kk], acc[rt], 0, 0, 0);
      }
    }
  }
  float bb = bl[(size_t)d * H_DIM + col];
  #pragma unroll
  for (int rt = 0; rt < 2; ++rt)
    #pragma unroll
    for (int j = 0; j < 4; ++j){
      int gr = rows_s[rt * 16 + kg * 4 + j];
      if (gr >= 0){
        float v = acc[rt][j] + bb;
        if (FINAL) hf[(size_t)gr * H_DIM + col] = v;
        else       hbo[(size_t)gr * H_DIM + col] = f2bf(relu_f(v));
      }
    }
}

// ---------- graph boundaries ----------
__global__ void k_goff(const int* __restrict__ batch, int* __restrict__ goff){
  int n = blockIdx.x * blockDim.x + threadIdx.x;
  if (n >= N_NODES) return;
  int b = batch[n];
  int bp = (n == 0) ? -1 : batch[n - 1];
  for (int g = bp + 1; g <= b; ++g) goff[g] = n;
  if (n == N_NODES - 1){
    for (int g = b + 1; g <= G_GRAPHS; ++g) goff[g] = N_NODES;
  }
}

// ---------- pooling ----------
__global__ __launch_bounds__(256) void k_pool(const float* __restrict__ h, const int* __restrict__ goff,
                                              float* __restrict__ pooled){
  __shared__ float4 sred[8][32];
  int g = blockIdx.x;
  int tid = threadIdx.x;
  int rg = tid >> 5, lane = tid & 31;
  int beg = goff[g], end = goff[g + 1];
  float4 acc = make_float4(0.f, 0.f, 0.f, 0.f);
  for (int n = beg + rg; n < end; n += 8){
    float4 v = ((const float4*)(h + (size_t)n * H_DIM))[lane];
    acc.x += v.x; acc.y += v.y; acc.z += v.z; acc.w += v.w;
  }
  sred[rg][lane] = acc;
  __syncthreads();
  if (tid < 32){
    float4 s = sred[0][tid];
    #pragma unroll
    for (int r = 1; r < 8; ++r){
      float4 v = sred[r][tid];
      s.x += v.x; s.y += v.y; s.z += v.z; s.w += v.w;
    }
    *(float4*)(pooled + (size_t)g * H_DIM + tid * 4) = s;
  }
}

// ---------- MLP ----------
__global__ void k_mlp1(const float* __restrict__ pooled, const float* __restrict__ W1,
                       const float* __restrict__ b1, float* __restrict__ T){
  int t = blockIdx.x * blockDim.x + threadIdx.x;
  if (t >= G_GRAPHS * H_DIM) return;
  int n = t >> 7, j = t & 127;
  float s = b1[j];
  for (int k = 0; k < H_DIM; ++k) s += pooled[n * H_DIM + k] * W1[k * H_DIM + j];
  T[t] = relu_f(s);
}

__global__ void k_mlp2(const float* __restrict__ T, const float* __restrict__ W2,
                       const float* __restrict__ b2, float* __restrict__ out){
  int t = blockIdx.x * blockDim.x + threadIdx.x;
  if (t >= G_GRAPHS * N_OUT) return;
  int n = t / N_OUT, j = t - n * N_OUT;
  float s = b2[j];
  for (int k = 0; k < H_DIM; ++k) s += T[n * H_DIM + k] * W2[k * N_OUT + j];
  out[t] = s;
}

extern "C" void kernel_launch(void* const* d_in, const int* in_sizes, int n_in,
                              void* d_out, int out_size, void* d_ws, size_t ws_size,
                              hipStream_t stream){
  const float* x      = (const float*)d_in[0];
  const int*   ei     = (const int*)d_in[1];
  const int*   ea     = (const int*)d_in[2];
  const int*   batch  = (const int*)d_in[3];
  const float* W0     = (const float*)d_in[4];
  const float* b0     = (const float*)d_in[5];
  const float* rWrel  = (const float*)d_in[6];
  const float* rWroot = (const float*)d_in[7];
  const float* rb     = (const float*)d_in[8];
  const float* mWl    = (const float*)d_in[9];
  const float* mbl    = (const float*)d_in[10];
  const float* mWr    = (const float*)d_in[11];
  const float* W1     = (const float*)d_in[12];
  const float* b1     = (const float*)d_in[13];
  const float* W2     = (const float*)d_in[14];
  const float* b2     = (const float*)d_in[15];
  float* out = (float*)d_out;

  const int* src = ei;
  const int* dst = ei + N_EDGES;

  char* ws = (char*)d_ws;
  size_t off = 0;
  auto alloc = [&](size_t bytes) -> void* {
    void* p = ws + off;
    off += (bytes + 255) & ~(size_t)255;
    return p;
  };
  u16* xb      = (u16*)alloc((size_t)N_NODES * H_DIM * 2);
  u16* hbA     = (u16*)alloc((size_t)N_NODES * H_DIM * 2);
  u16* hbB     = (u16*)alloc((size_t)N_NODES * H_DIM * 2);
  u16* meanb   = (u16*)alloc((size_t)N_NODES * R_REL * H_DIM * 2);
  u16* aggb    = meanb;  // reuse
  float* hf    = (float*)alloc((size_t)N_NODES * H_DIM * 4);
  u16* wt0     = (u16*)alloc((size_t)1 * 16384 * 2);
  u16* wtRel   = (u16*)alloc((size_t)NBLK * R_REL * 16384 * 2);
  u16* wtRoot  = (u16*)alloc((size_t)NBLK * 16384 * 2);
  u16* wtWl    = (u16*)alloc((size_t)NBLK * (MAXDEG + 1) * 16384 * 2);
  u16* wtWr    = (u16*)alloc((size_t)NBLK * (MAXDEG + 1) * 16384 * 2);
  float* pooled = (float*)alloc((size_t)G_GRAPHS * H_DIM * 4);
  float* T      = (float*)alloc((size_t)G_GRAPHS * H_DIM * 4);
  int* cnt4     = (int*)alloc((size_t)N_NODES * R_REL * 4);
  int* deg      = (int*)alloc((size_t)N_NODES * 4);
  int* row_ptr  = (int*)alloc((size_t)(N_NODES + 1) * 4);
  int* rel_off  = (int*)alloc((size_t)N_NODES * R_REL * 4);
  int* cursor   = (int*)alloc((size_t)N_NODES * R_REL * 4);
  int* esrc     = (int*)alloc((size_t)N_EDGES * 4);
  int* bsum     = (int*)alloc((size_t)NSCAN_BLK * 4);
  int* bbase    = (int*)alloc((size_t)NSCAN_BLK * 4);
  int* bhist    = (int*)alloc((size_t)NSCAN_BLK * (MAXDEG + 1) * 4);
  int* pbase    = (int*)alloc((size_t)NSCAN_BLK * (MAXDEG + 1) * 4);
  int* perm     = (int*)alloc((size_t)N_NODES * 4);
  int* bcount   = (int*)alloc(16 * 4);
  int* boff     = (int*)alloc(16 * 4);
  int* goff     = (int*)alloc((size_t)(G_GRAPHS + 1) * 4);

  hipMemsetAsync(cnt4, 0, (size_t)N_NODES * R_REL * 4, stream);
  hipMemsetAsync(cursor, 0, (size_t)N_NODES * R_REL * 4, stream);

  // graph structure
  k_cnt<<<(N_EDGES + 255) / 256, 256, 0, stream>>>(dst, ea, cnt4);
  k_scan_a<<<NSCAN_BLK, 256, 0, stream>>>(cnt4, deg, row_ptr, bsum, bhist);
  k_scan_b<<<1, 256, 0, stream>>>(bsum, bbase);
  k_scan_c<<<NSCAN_BLK, 256, 0, stream>>>(row_ptr, bbase, cnt4, rel_off);
  k_csr_fill<<<(N_EDGES + 255) / 256, 256, 0, stream>>>(src, dst, ea, rel_off, cursor, esrc);
  k_bscan<<<1, 64, 0, stream>>>(bhist, pbase, bcount, boff);
  k_bfill<<<NSCAN_BLK, 256, 0, stream>>>(deg, pbase, perm);
  k_goff<<<(N_NODES + 255) / 256, 256, 0, stream>>>(batch, goff);

  // weight + input conversion
  k_cvtW_all<<<55 * 16, 256, 0, stream>>>(W0, rWrel, rWroot, mWl, mWr,
                                          wt0, wtRel, wtRoot, wtWl, wtWr);
  k_cvtx<<<(N_NODES * H_DIM / 4 + 255) / 256, 256, 0, stream>>>(x, xb);

  k_gemm0<<<N_NODES / 32, 512, 0, stream>>>(xb, wt0, b0, hbA);

  u16* hin = hbA;
  u16* hout = hbB;
  for (int blk = 0; blk < NBLK; ++blk){
    k_rgcn_agg<<<N_NODES / 4, 256, 0, stream>>>(hin, rel_off, row_ptr, esrc, meanb);
    k_rgcn_gemm<<<N_NODES / 32, 512, 0, stream>>>(meanb, hin,
        wtRel + (size_t)blk * R_REL * 16384,
        wtRoot + (size_t)blk * 16384,
        rb + (size_t)blk * H_DIM, hout);
    { u16* tmp = hin; hin = hout; hout = tmp; }

    k_mf_agg<<<N_NODES / 4, 256, 0, stream>>>(hin, row_ptr, esrc, aggb);
    const u16* wl_b = wtWl + (size_t)blk * (MAXDEG + 1) * 16384;
    const u16* wr_b = wtWr + (size_t)blk * (MAXDEG + 1) * 16384;
    const float* bl_b = mbl + (size_t)blk * (MAXDEG + 1) * H_DIM;
    int grid_mf = N_NODES / 32 + MAXDEG + 1;   // 1261 upper bound on bucket tiles
    if (blk == NBLK - 1)
      k_mf_gemm<1><<<grid_mf, 512, 0, stream>>>(aggb, hin, wl_b, wr_b, bl_b,
                                                bcount, boff, perm, hout, hf);
    else
      k_mf_gemm<0><<<grid_mf, 512, 0, stream>>>(aggb, hin, wl_b, wr_b, bl_b,
                                                bcount, boff, perm, hout, hf);
    { u16* tmp = hin; hin = hout; hout = tmp; }
  }

  k_pool<<<G_GRAPHS, 256, 0, stream>>>(hf, goff, pooled);
  k_mlp1<<<(G_GRAPHS * H_DIM + 255) / 256, 256, 0, stream>>>(pooled, W1, b1, T);
  k_mlp2<<<(G_GRAPHS * N_OUT + 255) / 256, 256, 0, stream>>>(T, W2, b2, out);
}